// Round 1
// baseline (928.277 us; speedup 1.0000x reference)
//
#include <hip/hip_runtime.h>
#include <cstdint>
#include <cstddef>

// ---------------------------------------------------------------------------
// HeliosAttention: hs->QKV proj -> RMSNorm -> RoPE -> 2-segment SDPA -> out proj
// B=2 S=3072 DIM=2048 H=16 HD=128 hist=1024
// ---------------------------------------------------------------------------

typedef __bf16 bf16_t;
typedef __attribute__((ext_vector_type(8))) __bf16 bf16x8;
typedef __attribute__((ext_vector_type(4))) __bf16 bf16x4;
typedef __attribute__((ext_vector_type(4))) float f32x4;
typedef __attribute__((ext_vector_type(4))) unsigned int u32x4;

#define NB   2
#define NS   3072
#define ND   2048
#define NH   16
#define NHD  128
#define NTOK (NB * NS)      // 6144
#define NHIST 1024

__device__ __forceinline__ f32x4 mfma16(bf16x8 a, bf16x8 b, f32x4 c) {
    return __builtin_amdgcn_mfma_f32_16x16x32_bf16(a, b, c, 0, 0, 0);
}

// ---------------- fp32 -> bf16 elementwise cast ----------------
__global__ __launch_bounds__(256) void cast_bf16_kernel(const float* __restrict__ src,
                                                        bf16_t* __restrict__ dst, int n4) {
    int i = blockIdx.x * 256 + threadIdx.x;
    if (i >= n4) return;
    f32x4 v = ((const f32x4*)src)[i];
    bf16x4 o;
    o[0] = (bf16_t)v[0]; o[1] = (bf16_t)v[1];
    o[2] = (bf16_t)v[2]; o[3] = (bf16_t)v[3];
    ((bf16x4*)dst)[i] = o;
}

// ---------------- C(f32) = A(bf16,MxK) * B(bf16,NxK)^T + bias ----------------
// 128x128 tile, BK=32, 4 waves in 2x2, each wave 4x4 grid of 16x16x32 MFMAs.
// LDS row stride 40 elements (80B): 16B-aligned for ds_read_b128, bank-optimal.
__global__ __launch_bounds__(256) void gemm_bt(const bf16_t* __restrict__ A,
                                               const bf16_t* __restrict__ Bm,
                                               const float* __restrict__ bias,
                                               float* __restrict__ C,
                                               int M, int N, int K) {
    __shared__ bf16_t As[128 * 40];
    __shared__ bf16_t Bs[128 * 40];
    const int tid  = threadIdx.x;
    const int wid  = tid >> 6, lane = tid & 63;
    const int g    = lane >> 4, c = lane & 15;
    const int m0   = blockIdx.y * 128, n0 = blockIdx.x * 128;
    const int srow = tid >> 2, skc = tid & 3;        // staging: 64 rows x 4 chunks
    const int wm   = (wid & 1) * 64, wn = (wid >> 1) * 64;

    const u32x4* Ap0 = (const u32x4*)(A + (size_t)(m0 + srow) * K + skc * 8);
    const u32x4* Ap1 = (const u32x4*)(A + (size_t)(m0 + srow + 64) * K + skc * 8);
    const u32x4* Bp0 = (const u32x4*)(Bm + (size_t)(n0 + srow) * K + skc * 8);
    const u32x4* Bp1 = (const u32x4*)(Bm + (size_t)(n0 + srow + 64) * K + skc * 8);

    u32x4 ra0 = Ap0[0], ra1 = Ap1[0], rb0 = Bp0[0], rb1 = Bp1[0];

    f32x4 acc[4][4];
#pragma unroll
    for (int mi = 0; mi < 4; mi++)
#pragma unroll
        for (int ni = 0; ni < 4; ni++)
            acc[mi][ni] = (f32x4){0.f, 0.f, 0.f, 0.f};

    const int nsteps = K / 32;
    for (int ks = 0; ks < nsteps; ks++) {
        __syncthreads();                      // previous iteration's readers done
        *(u32x4*)&As[srow * 40 + skc * 8]        = ra0;
        *(u32x4*)&As[(srow + 64) * 40 + skc * 8] = ra1;
        *(u32x4*)&Bs[srow * 40 + skc * 8]        = rb0;
        *(u32x4*)&Bs[(srow + 64) * 40 + skc * 8] = rb1;
        __syncthreads();
        if (ks + 1 < nsteps) {                // prefetch next K-slice (in flight over MFMAs)
            int off = (ks + 1) * 4;           // 4 u32x4 = 32 elements along K
            ra0 = Ap0[off]; ra1 = Ap1[off]; rb0 = Bp0[off]; rb1 = Bp1[off];
        }
        bf16x8 af[4], bfr[4];
#pragma unroll
        for (int mi = 0; mi < 4; mi++)
            af[mi] = *(const bf16x8*)&As[(wm + mi * 16 + c) * 40 + g * 8];
#pragma unroll
        for (int ni = 0; ni < 4; ni++)
            bfr[ni] = *(const bf16x8*)&Bs[(wn + ni * 16 + c) * 40 + g * 8];
#pragma unroll
        for (int mi = 0; mi < 4; mi++)
#pragma unroll
            for (int ni = 0; ni < 4; ni++)
                acc[mi][ni] = mfma16(af[mi], bfr[ni], acc[mi][ni]);
    }

    float bi[4];
#pragma unroll
    for (int ni = 0; ni < 4; ni++) bi[ni] = bias[n0 + wn + ni * 16 + c];
#pragma unroll
    for (int mi = 0; mi < 4; mi++) {
#pragma unroll
        for (int i = 0; i < 4; i++) {
            int m = m0 + wm + mi * 16 + g * 4 + i;   // C/D: row=(lane>>4)*4+reg, col=lane&15
            float* crow = C + (size_t)m * N + n0 + wn + c;
#pragma unroll
            for (int ni = 0; ni < 4; ni++) crow[ni * 16] = acc[mi][ni][i] + bi[ni];
        }
    }
}

// ---------------- RMSNorm + RoPE + cast, writes [bh][s][hd] bf16 ----------------
// outscale folds (1/sqrt(128))*log2(e) into Q so attention softmax is exp2-domain.
__global__ __launch_bounds__(256) void rmsrope_kernel(const float* __restrict__ X,
                                                      const float* __restrict__ gvec,
                                                      const float* __restrict__ rot,
                                                      bf16_t* __restrict__ dst,
                                                      float outscale) {
    const int t = blockIdx.x;                 // token 0..6143
    const int b = t / NS, s = t % NS;
    const int tid = threadIdx.x;
    const int lane = tid & 63, wid = tid >> 6;
    const float* row = X + (size_t)t * ND;

    f32x4 x0 = *(const f32x4*)(row + tid * 8);
    f32x4 x1 = *(const f32x4*)(row + tid * 8 + 4);
    float ss = 0.f;
#pragma unroll
    for (int u = 0; u < 4; u++) ss += x0[u] * x0[u] + x1[u] * x1[u];
#pragma unroll
    for (int msk = 1; msk < 64; msk <<= 1) ss += __shfl_xor(ss, msk);
    __shared__ float red[4];
    if (lane == 0) red[wid] = ss;
    __syncthreads();
    float tot = red[0] + red[1] + red[2] + red[3];
    float scl = rsqrtf(tot * (1.f / (float)ND) + 1e-6f);

    f32x4 g0 = *(const f32x4*)(gvec + tid * 8);
    f32x4 g1 = *(const f32x4*)(gvec + tid * 8 + 4);
    float y[8];
#pragma unroll
    for (int u = 0; u < 4; u++) { y[u] = x0[u] * scl * g0[u]; y[4 + u] = x1[u] * scl * g1[u]; }

    const int dim = tid * 8, hd = dim & (NHD - 1), h = dim >> 7;
    const float* rr = rot + (size_t)s * (2 * NHD);
    bf16x8 o;
#pragma unroll
    for (int u = 0; u < 4; u++) {
        float cc = rr[hd + 2 * u];               // cos = fc[:128] even idx
        float sn = rr[NHD + hd + 2 * u + 1];     // sin = fc[128:] odd idx
        float e = y[2 * u], od = y[2 * u + 1];
        o[2 * u]     = (bf16_t)((e * cc - od * sn) * outscale);
        o[2 * u + 1] = (bf16_t)((e * sn + od * cc) * outscale);
    }
    *(bf16x8*)(dst + (((size_t)b * NH + h) * NS + s) * NHD + hd) = o;
}

// ---------------- V: +bias done in GEMM; transpose [b][s][h*d] -> [bh][d][s] bf16 ----------
__global__ __launch_bounds__(256) void vtrans_kernel(const float* __restrict__ X,
                                                     bf16_t* __restrict__ VTg) {
    __shared__ bf16_t T[128 * 65];
    const int tid = threadIdx.x;
    const int st = blockIdx.x;                // s-tile of 64
    const int bh = blockIdx.y;
    const int b = bh >> 4, h = bh & 15;
    const int ds = tid >> 4, ssx = tid & 15;
#pragma unroll
    for (int i = 0; i < 4; i++) {
        int sl = ssx + i * 16;
        const float* xr = X + (size_t)(b * NS + st * 64 + sl) * ND + h * NHD;
#pragma unroll
        for (int j = 0; j < 2; j++) {
            int d = ds * 8 + j * 4;
            f32x4 v = *(const f32x4*)(xr + d);
            T[(d + 0) * 65 + sl] = (bf16_t)v[0];
            T[(d + 1) * 65 + sl] = (bf16_t)v[1];
            T[(d + 2) * 65 + sl] = (bf16_t)v[2];
            T[(d + 3) * 65 + sl] = (bf16_t)v[3];
        }
    }
    __syncthreads();
#pragma unroll
    for (int q = 0; q < 4; q++) {
        int chunk = q * 256 + tid;
        int d = chunk >> 3, sc8 = chunk & 7;
        bf16x8 o;
#pragma unroll
        for (int u = 0; u < 8; u++) o[u] = T[d * 65 + sc8 * 8 + u];
        *(bf16x8*)(VTg + ((size_t)bh * NHD + d) * NS + st * 64 + sc8 * 8) = o;
    }
}

// ---------------- flash attention ----------------
// grid (48 qtiles, 32 bh). 4 waves/block, 16 queries/wave, K-blocks of 32.
// Q pre-scaled by log2(e)/sqrt(128) -> softmax via exp2.
// qtile<16 (tokens<1024) attends keys [0,1024); else keys [0,3072).
__global__ __launch_bounds__(256) void attn_kernel(const bf16_t* __restrict__ Qg,
                                                   const bf16_t* __restrict__ Kg,
                                                   const bf16_t* __restrict__ Vg,
                                                   bf16_t* __restrict__ Og) {
    __shared__ bf16_t Ks[32 * 136];    // [key][d], stride 136
    __shared__ bf16_t Vs[128 * 40];    // [d][key], stride 40
    __shared__ bf16_t Ps[4][16 * 40];  // per-wave P round-trip, [q][key], stride 40
    const int tid = threadIdx.x;
    const int wid = tid >> 6, lane = tid & 63;
    const int g = lane >> 4, c = lane & 15;
    const int qb = blockIdx.x, bh = blockIdx.y;
    const int q0 = qb * 64 + wid * 16;
    const int kmax = (qb * 64 < NHIST) ? NHIST : NS;

    // Q fragments, held in registers for the whole kernel
    bf16x8 qf[4];
    const bf16_t* qrow = Qg + ((size_t)bh * NS + q0 + c) * NHD;
#pragma unroll
    for (int d = 0; d < 4; d++) qf[d] = *(const bf16x8*)(qrow + d * 32 + g * 8);

    f32x4 o[8];
#pragma unroll
    for (int nt = 0; nt < 8; nt++) o[nt] = (f32x4){0.f, 0.f, 0.f, 0.f};
    float m_i[4], l_i[4];
#pragma unroll
    for (int i = 0; i < 4; i++) { m_i[i] = -1e30f; l_i[i] = 0.f; }

    // staging assignments
    const int skey = tid >> 3, sch = tid & 7;     // K: 32 rows x 8 threads
    const int svd = tid >> 1, svh = tid & 1;      // V: 128 rows x 2 threads

    for (int kb = 0; kb < kmax; kb += 32) {
        __syncthreads();    // previous iteration's LDS readers done
        {
            const u32x4* ksrc = (const u32x4*)(Kg + ((size_t)bh * NS + kb + skey) * NHD);
            u32x4 k0 = ksrc[sch], k1 = ksrc[sch + 8];
            *(u32x4*)&Ks[skey * 136 + sch * 8]       = k0;
            *(u32x4*)&Ks[skey * 136 + (sch + 8) * 8] = k1;
            const u32x4* vsrc = (const u32x4*)(Vg + ((size_t)bh * NHD + svd) * NS + kb);
            u32x4 v0 = vsrc[svh * 2], v1 = vsrc[svh * 2 + 1];
            *(u32x4*)&Vs[svd * 40 + svh * 16]     = v0;
            *(u32x4*)&Vs[svd * 40 + svh * 16 + 8] = v1;
        }
        __syncthreads();

        // S = Q K^T  (two 16-key subtiles)
        f32x4 sv[2];
        sv[0] = (f32x4){0.f, 0.f, 0.f, 0.f};
        sv[1] = (f32x4){0.f, 0.f, 0.f, 0.f};
#pragma unroll
        for (int kt = 0; kt < 2; kt++)
#pragma unroll
            for (int d = 0; d < 4; d++) {
                bf16x8 kf = *(const bf16x8*)&Ks[(kt * 16 + c) * 136 + d * 32 + g * 8];
                sv[kt] = mfma16(qf[d], kf, sv[kt]);
            }

        // online softmax (log2 domain); row stats live on the same lanes as O rows
        float mnew[4], al[4], p[2][4];
#pragma unroll
        for (int i = 0; i < 4; i++) {
            float mx = fmaxf(sv[0][i], sv[1][i]);
#pragma unroll
            for (int msk = 1; msk < 16; msk <<= 1) mx = fmaxf(mx, __shfl_xor(mx, msk));
            mnew[i] = fmaxf(m_i[i], mx);
            al[i] = exp2f(m_i[i] - mnew[i]);
            m_i[i] = mnew[i];
        }
#pragma unroll
        for (int kt = 0; kt < 2; kt++)
#pragma unroll
            for (int i = 0; i < 4; i++) p[kt][i] = exp2f(sv[kt][i] - mnew[i]);
#pragma unroll
        for (int i = 0; i < 4; i++) {
            float r = p[0][i] + p[1][i];
#pragma unroll
            for (int msk = 1; msk < 16; msk <<= 1) r += __shfl_xor(r, msk);
            l_i[i] = l_i[i] * al[i] + r;
        }
#pragma unroll
        for (int nt = 0; nt < 8; nt++)
#pragma unroll
            for (int i = 0; i < 4; i++) o[nt][i] *= al[i];

        // P: C-layout -> A-operand layout via per-wave LDS round-trip
        bf16_t* pw = &Ps[wid][0];
#pragma unroll
        for (int kt = 0; kt < 2; kt++)
#pragma unroll
            for (int i = 0; i < 4; i++)
                pw[(g * 4 + i) * 40 + kt * 16 + c] = (bf16_t)p[kt][i];
        bf16x8 pf = *(const bf16x8*)&pw[c * 40 + g * 8];

        // O += P V
#pragma unroll
        for (int nt = 0; nt < 8; nt++) {
            bf16x8 vf = *(const bf16x8*)&Vs[(nt * 16 + c) * 40 + g * 8];
            o[nt] = mfma16(pf, vf, o[nt]);
        }
    }

    // normalize + store [b][s][h][d] bf16
    const int b = bh >> 4, h = bh & 15;
#pragma unroll
    for (int i = 0; i < 4; i++) {
        float inv = 1.0f / l_i[i];
        int q = q0 + g * 4 + i;
        bf16_t* orow = Og + (((size_t)b * NS + q) * NH + h) * NHD;
#pragma unroll
        for (int nt = 0; nt < 8; nt++) orow[nt * 16 + c] = (bf16_t)(o[nt][i] * inv);
    }
}

// ---------------------------------------------------------------------------
extern "C" void kernel_launch(void* const* d_in, const int* in_sizes, int n_in,
                              void* d_out, int out_size, void* d_ws, size_t ws_size,
                              hipStream_t stream) {
    const float* hs  = (const float*)d_in[0];
    const float* rot = (const float*)d_in[1];
    const float* Wq  = (const float*)d_in[2];
    const float* bq  = (const float*)d_in[3];
    const float* Wk  = (const float*)d_in[4];
    const float* bk  = (const float*)d_in[5];
    const float* Wv  = (const float*)d_in[6];
    const float* bv  = (const float*)d_in[7];
    const float* gq  = (const float*)d_in[8];
    const float* gk  = (const float*)d_in[9];
    const float* Wo  = (const float*)d_in[10];
    const float* bo  = (const float*)d_in[11];
    float* out = (float*)d_out;

    char* ws = (char*)d_ws;
    bf16_t* Xb  = (bf16_t*)(ws + 0);            // 6144x2048 bf16 = 25165824 B
    bf16_t* Wqb = (bf16_t*)(ws + 25165824);     // 2048x2048 bf16 = 8388608 B
    bf16_t* Wkb = (bf16_t*)(ws + 33554432);
    bf16_t* Wvb = (bf16_t*)(ws + 41943040);
    bf16_t* Wob = (bf16_t*)(ws + 50331648);
    bf16_t* Qb  = (bf16_t*)(ws + 58720256);     // [bh][s][hd] 25165824 B
    bf16_t* Kb  = (bf16_t*)(ws + 83886080);
    bf16_t* VTb = (bf16_t*)(ws + 109051904);    // [bh][hd][s]
    bf16_t* Ob  = (bf16_t*)(ws + 134217728);    // [b][s][h][hd]
    float* Ff = out;  // fp32 proj scratch; final GEMM fully overwrites d_out

    const float QSCALE = 1.4426950408889634f * 0.08838834764831845f; // log2(e)/sqrt(128)

    // 1. casts
    cast_bf16_kernel<<<12288, 256, 0, stream>>>(hs, Xb, NTOK * ND / 4);
    cast_bf16_kernel<<<4096, 256, 0, stream>>>(Wq, Wqb, ND * ND / 4);
    cast_bf16_kernel<<<4096, 256, 0, stream>>>(Wk, Wkb, ND * ND / 4);
    cast_bf16_kernel<<<4096, 256, 0, stream>>>(Wv, Wvb, ND * ND / 4);
    cast_bf16_kernel<<<4096, 256, 0, stream>>>(Wo, Wob, ND * ND / 4);

    dim3 gg(ND / 128, NTOK / 128);   // (16, 48)

    // 2. Q proj -> RMS+RoPE (score scale folded into Q)
    gemm_bt<<<gg, 256, 0, stream>>>(Xb, Wqb, bq, Ff, NTOK, ND, ND);
    rmsrope_kernel<<<NTOK, 256, 0, stream>>>(Ff, gq, rot, Qb, QSCALE);
    // 3. K proj -> RMS+RoPE
    gemm_bt<<<gg, 256, 0, stream>>>(Xb, Wkb, bk, Ff, NTOK, ND, ND);
    rmsrope_kernel<<<NTOK, 256, 0, stream>>>(Ff, gk, rot, Kb, 1.0f);
    // 4. V proj (+bias in GEMM) -> transpose
    gemm_bt<<<gg, 256, 0, stream>>>(Xb, Wvb, bv, Ff, NTOK, ND, ND);
    vtrans_kernel<<<dim3(48, 32), 256, 0, stream>>>(Ff, VTb);
    // 5. attention
    attn_kernel<<<dim3(48, 32), 256, 0, stream>>>(Qb, Kb, VTb, Ob);
    // 6. output projection
    gemm_bt<<<gg, 256, 0, stream>>>(Ob, Wob, bo, out, NTOK, ND, ND);
}

// Round 2
// 800.235 us; speedup vs baseline: 1.1600x; 1.1600x over previous
//
#include <hip/hip_runtime.h>
#include <cstdint>
#include <cstddef>

// ---------------------------------------------------------------------------
// HeliosAttention: hs->QKV proj -> RMSNorm -> RoPE -> 2-segment SDPA -> out proj
// B=2 S=3072 DIM=2048 H=16 HD=128 hist=1024
// ---------------------------------------------------------------------------

typedef __bf16 bf16_t;
typedef __attribute__((ext_vector_type(8))) __bf16 bf16x8;
typedef __attribute__((ext_vector_type(4))) __bf16 bf16x4;
typedef __attribute__((ext_vector_type(4))) float f32x4;
typedef __attribute__((ext_vector_type(4))) unsigned int u32x4;

#define NB   2
#define NS   3072
#define ND   2048
#define NH   16
#define NHD  128
#define NTOK (NB * NS)      // 6144
#define NHIST 1024

__device__ __forceinline__ f32x4 mfma16(bf16x8 a, bf16x8 b, f32x4 c) {
    return __builtin_amdgcn_mfma_f32_16x16x32_bf16(a, b, c, 0, 0, 0);
}

// async global->LDS, 16B per lane. LDS dst MUST be wave-uniform base + lane*16.
__device__ __forceinline__ void async16(const bf16_t* gsrc, bf16_t* ldst) {
    __builtin_amdgcn_global_load_lds(
        (const __attribute__((address_space(1))) void*)gsrc,
        (__attribute__((address_space(3))) void*)ldst,
        16, 0, 0);
}

// ---------------- fp32 -> bf16 elementwise cast ----------------
__global__ __launch_bounds__(256) void cast_bf16_kernel(const float* __restrict__ src,
                                                        bf16_t* __restrict__ dst, int n4) {
    int i = blockIdx.x * 256 + threadIdx.x;
    if (i >= n4) return;
    f32x4 v = ((const f32x4*)src)[i];
    bf16x4 o;
    o[0] = (bf16_t)v[0]; o[1] = (bf16_t)v[1];
    o[2] = (bf16_t)v[2]; o[3] = (bf16_t)v[3];
    ((bf16x4*)dst)[i] = o;
}

// ---------------- C(f32) = A(bf16,MxK) * B(bf16,NxK)^T + bias ----------------
// m97 structure: 128x128 tile, BK=32, global_load_lds width=16 staging into
// UNPADDED stride-32 LDS (lane-contiguous, required by global_load_lds).
// Fragment b128 reads on stride-32 rows: 8 start-banks, 8-cycle structural min.
__global__ __launch_bounds__(256) void gemm_bt(const bf16_t* __restrict__ A,
                                               const bf16_t* __restrict__ Bm,
                                               const float* __restrict__ bias,
                                               float* __restrict__ C,
                                               int M, int N, int K) {
    __shared__ bf16_t As[128 * 32];
    __shared__ bf16_t Bs[128 * 32];
    const int tid  = threadIdx.x;
    const int wid  = tid >> 6, lane = tid & 63;
    const int g    = lane >> 4, c = lane & 15;
    const int m0   = blockIdx.y * 128, n0 = blockIdx.x * 128;
    const int wm   = (wid & 1) * 64, wn = (wid >> 1) * 64;
    const int srow = tid >> 2, skc = tid & 3;   // thread t: row t>>2, 8-elem chunk t&3

    const bf16_t* Ag0 = A + (size_t)(m0 + srow) * K + skc * 8;
    const bf16_t* Ag1 = A + (size_t)(m0 + srow + 64) * K + skc * 8;
    const bf16_t* Bg0 = Bm + (size_t)(n0 + srow) * K + skc * 8;
    const bf16_t* Bg1 = Bm + (size_t)(n0 + srow + 64) * K + skc * 8;
    bf16_t* Asd0 = As + tid * 8;            // == (srow*32 + skc*8): lane-contiguous
    bf16_t* Asd1 = As + 2048 + tid * 8;
    bf16_t* Bsd0 = Bs + tid * 8;
    bf16_t* Bsd1 = Bs + 2048 + tid * 8;

    f32x4 acc[4][4];
#pragma unroll
    for (int mi = 0; mi < 4; mi++)
#pragma unroll
        for (int ni = 0; ni < 4; ni++)
            acc[mi][ni] = (f32x4){0.f, 0.f, 0.f, 0.f};

    const int nsteps = K / 32;
    for (int ks = 0; ks < nsteps; ks++) {
        __syncthreads();                    // prev tile's readers done
        async16(Ag0 + ks * 32, Asd0);
        async16(Ag1 + ks * 32, Asd1);
        async16(Bg0 + ks * 32, Bsd0);
        async16(Bg1 + ks * 32, Bsd1);
        __syncthreads();                    // implicit vmcnt(0) drain: tile ready

        bf16x8 af[4], bfr[4];
#pragma unroll
        for (int mi = 0; mi < 4; mi++)
            af[mi] = *(const bf16x8*)&As[(wm + mi * 16 + c) * 32 + g * 8];
#pragma unroll
        for (int ni = 0; ni < 4; ni++)
            bfr[ni] = *(const bf16x8*)&Bs[(wn + ni * 16 + c) * 32 + g * 8];
#pragma unroll
        for (int mi = 0; mi < 4; mi++)
#pragma unroll
            for (int ni = 0; ni < 4; ni++)
                acc[mi][ni] = mfma16(af[mi], bfr[ni], acc[mi][ni]);
    }

    float bi[4];
#pragma unroll
    for (int ni = 0; ni < 4; ni++) bi[ni] = bias[n0 + wn + ni * 16 + c];
#pragma unroll
    for (int mi = 0; mi < 4; mi++) {
#pragma unroll
        for (int i = 0; i < 4; i++) {
            int m = m0 + wm + mi * 16 + g * 4 + i;   // C/D: row=(lane>>4)*4+reg, col=lane&15
            float* crow = C + (size_t)m * N + n0 + wn + c;
#pragma unroll
            for (int ni = 0; ni < 4; ni++) crow[ni * 16] = acc[mi][ni][i] + bi[ni];
        }
    }
}

// ---------------- RMSNorm + RoPE + cast, writes [bh][s][hd] bf16 ----------------
// outscale folds (1/sqrt(128))*log2(e) into Q so attention softmax is exp2-domain.
__global__ __launch_bounds__(256) void rmsrope_kernel(const float* __restrict__ X,
                                                      const float* __restrict__ gvec,
                                                      const float* __restrict__ rot,
                                                      bf16_t* __restrict__ dst,
                                                      float outscale) {
    const int t = blockIdx.x;                 // token 0..6143
    const int b = t / NS, s = t % NS;
    const int tid = threadIdx.x;
    const int lane = tid & 63, wid = tid >> 6;
    const float* row = X + (size_t)t * ND;

    f32x4 x0 = *(const f32x4*)(row + tid * 8);
    f32x4 x1 = *(const f32x4*)(row + tid * 8 + 4);
    float ss = 0.f;
#pragma unroll
    for (int u = 0; u < 4; u++) ss += x0[u] * x0[u] + x1[u] * x1[u];
#pragma unroll
    for (int msk = 1; msk < 64; msk <<= 1) ss += __shfl_xor(ss, msk);
    __shared__ float red[4];
    if (lane == 0) red[wid] = ss;
    __syncthreads();
    float tot = red[0] + red[1] + red[2] + red[3];
    float scl = rsqrtf(tot * (1.f / (float)ND) + 1e-6f);

    f32x4 g0 = *(const f32x4*)(gvec + tid * 8);
    f32x4 g1 = *(const f32x4*)(gvec + tid * 8 + 4);
    float y[8];
#pragma unroll
    for (int u = 0; u < 4; u++) { y[u] = x0[u] * scl * g0[u]; y[4 + u] = x1[u] * scl * g1[u]; }

    const int dim = tid * 8, hd = dim & (NHD - 1), h = dim >> 7;
    const float* rr = rot + (size_t)s * (2 * NHD);
    bf16x8 o;
#pragma unroll
    for (int u = 0; u < 4; u++) {
        float cc = rr[hd + 2 * u];               // cos = fc[:128] even idx
        float sn = rr[NHD + hd + 2 * u + 1];     // sin = fc[128:] odd idx
        float e = y[2 * u], od = y[2 * u + 1];
        o[2 * u]     = (bf16_t)((e * cc - od * sn) * outscale);
        o[2 * u + 1] = (bf16_t)((e * sn + od * cc) * outscale);
    }
    *(bf16x8*)(dst + (((size_t)b * NH + h) * NS + s) * NHD + hd) = o;
}

// ---------------- V: +bias done in GEMM; transpose [b][s][h*d] -> [bh][d][s] bf16 ----------
__global__ __launch_bounds__(256) void vtrans_kernel(const float* __restrict__ X,
                                                     bf16_t* __restrict__ VTg) {
    __shared__ bf16_t T[128 * 65];
    const int tid = threadIdx.x;
    const int st = blockIdx.x;                // s-tile of 64
    const int bh = blockIdx.y;
    const int b = bh >> 4, h = bh & 15;
    const int ds = tid >> 4, ssx = tid & 15;
#pragma unroll
    for (int i = 0; i < 4; i++) {
        int sl = ssx + i * 16;
        const float* xr = X + (size_t)(b * NS + st * 64 + sl) * ND + h * NHD;
#pragma unroll
        for (int j = 0; j < 2; j++) {
            int d = ds * 8 + j * 4;
            f32x4 v = *(const f32x4*)(xr + d);
            T[(d + 0) * 65 + sl] = (bf16_t)v[0];
            T[(d + 1) * 65 + sl] = (bf16_t)v[1];
            T[(d + 2) * 65 + sl] = (bf16_t)v[2];
            T[(d + 3) * 65 + sl] = (bf16_t)v[3];
        }
    }
    __syncthreads();
#pragma unroll
    for (int q = 0; q < 4; q++) {
        int chunk = q * 256 + tid;
        int d = chunk >> 3, sc8 = chunk & 7;
        bf16x8 o;
#pragma unroll
        for (int u = 0; u < 8; u++) o[u] = T[d * 65 + sc8 * 8 + u];
        *(bf16x8*)(VTg + ((size_t)bh * NHD + d) * NS + st * 64 + sc8 * 8) = o;
    }
}

// ---------------- flash attention (S^T trick + fixed-max softmax) ----------------
// grid (24 qtiles of 128, 32 bh). 4 waves/block, 32 queries/wave (2 q-frags),
// K-blocks of 32. Q pre-scaled by log2(e)/sqrt(128) -> scores in log2 domain.
// Scores are statistically bounded (RMS-normed Q,K): fixed max FM=18 is safe
// (fp32 l overflows only past 2^127). No online max, no rescale, l deferred.
// QK computed as S^T = mfma(K-frag, Q-frag): P^T lands k-contiguous per lane ->
// P round-trip is 2x ds_write_b64 + 1x ds_read_b128 (structural-min banks).
// PV computed as O^T = mfma(V^T-frag, P-frag): V^T A-frag == Vs[d][key] read;
// O^T col=q lands on same lane as l -> in-lane normalize, vectorized store.
__global__ __launch_bounds__(256) void attn_kernel(const bf16_t* __restrict__ Qg,
                                                   const bf16_t* __restrict__ Kg,
                                                   const bf16_t* __restrict__ Vg,
                                                   bf16_t* __restrict__ Og) {
    __shared__ bf16_t Ks[32 * 136];       // [key][d], stride 136
    __shared__ bf16_t Vs[128 * 40];       // [d][key], stride 40
    __shared__ bf16_t Ps[4][2][16 * 40];  // per-wave per-qfrag, [q][k], kstride 40
    const int tid = threadIdx.x;
    const int wid = tid >> 6, lane = tid & 63;
    const int g = lane >> 4, c = lane & 15;
    const int qb = blockIdx.x, bh = blockIdx.y;
    const int q0 = qb * 128 + wid * 32;
    const int kmax = (qb * 128 < NHIST) ? NHIST : NS;
    const float FM = 18.0f;

    // Q B-fragments for 2 q-subtiles, held in registers for the whole kernel
    bf16x8 qf[2][4];
#pragma unroll
    for (int f = 0; f < 2; f++) {
        const bf16_t* qrow = Qg + ((size_t)bh * NS + q0 + f * 16 + c) * NHD;
#pragma unroll
        for (int d = 0; d < 4; d++) qf[f][d] = *(const bf16x8*)(qrow + d * 32 + g * 8);
    }

    f32x4 o[2][8];
#pragma unroll
    for (int f = 0; f < 2; f++)
#pragma unroll
        for (int nt = 0; nt < 8; nt++) o[f][nt] = (f32x4){0.f, 0.f, 0.f, 0.f};
    float l[2] = {0.f, 0.f};

    // staging assignments
    const int skey = tid >> 3, sch = tid & 7;     // K: 32 rows x 8 threads
    const int svd = tid >> 1, svh = tid & 1;      // V: 128 rows x 2 threads

    for (int kb = 0; kb < kmax; kb += 32) {
        __syncthreads();    // previous iteration's LDS readers done
        {
            const u32x4* ksrc = (const u32x4*)(Kg + ((size_t)bh * NS + kb + skey) * NHD);
            u32x4 k0 = ksrc[sch], k1 = ksrc[sch + 8];
            *(u32x4*)&Ks[skey * 136 + sch * 8]       = k0;
            *(u32x4*)&Ks[skey * 136 + (sch + 8) * 8] = k1;
            const u32x4* vsrc = (const u32x4*)(Vg + ((size_t)bh * NHD + svd) * NS + kb);
            u32x4 v0 = vsrc[svh * 2], v1 = vsrc[svh * 2 + 1];
            *(u32x4*)&Vs[svd * 40 + svh * 16]     = v0;
            *(u32x4*)&Vs[svd * 40 + svh * 16 + 8] = v1;
        }
        __syncthreads();

        // S^T = mfma(K-frag, Q-frag): sv[f][kt] C-layout holds
        // S[q = q0+f*16+c][key = kb + kt*16 + g*4 + i]
        f32x4 sv[2][2];
#pragma unroll
        for (int f = 0; f < 2; f++)
#pragma unroll
            for (int kt = 0; kt < 2; kt++) sv[f][kt] = (f32x4){0.f, 0.f, 0.f, 0.f};
#pragma unroll
        for (int kt = 0; kt < 2; kt++)
#pragma unroll
            for (int dd = 0; dd < 4; dd++) {
                bf16x8 kf = *(const bf16x8*)&Ks[(kt * 16 + c) * 136 + dd * 32 + g * 8];
#pragma unroll
                for (int f = 0; f < 2; f++) sv[f][kt] = mfma16(kf, qf[f][dd], sv[f][kt]);
            }

        // fixed-max softmax: p = exp2(s - FM); l accumulates per-lane (deferred
        // reduction); pack k-contiguous bf16x4 -> Ps[q][k]
#pragma unroll
        for (int f = 0; f < 2; f++) {
#pragma unroll
            for (int kt = 0; kt < 2; kt++) {
                bf16x4 pk;
#pragma unroll
                for (int i = 0; i < 4; i++) {
                    float pv = exp2f(sv[f][kt][i] - FM);
                    l[f] += pv;
                    pk[i] = (bf16_t)pv;
                }
                *(bf16x4*)&Ps[wid][f][c * 40 + kt * 16 + g * 4] = pk;
            }
        }
        bf16x8 pf0 = *(const bf16x8*)&Ps[wid][0][c * 40 + g * 8];
        bf16x8 pf1 = *(const bf16x8*)&Ps[wid][1][c * 40 + g * 8];

        // O^T += mfma(V^T-frag, P-frag), contraction over the 32 keys
#pragma unroll
        for (int nt = 0; nt < 8; nt++) {
            bf16x8 vf = *(const bf16x8*)&Vs[(nt * 16 + c) * 40 + g * 8];
            o[0][nt] = mfma16(vf, pf0, o[0][nt]);
            o[1][nt] = mfma16(vf, pf1, o[1][nt]);
        }
    }

    // deferred l reduction (over the 4 g-lane groups), normalize, store
    const int b = bh >> 4, h = bh & 15;
#pragma unroll
    for (int f = 0; f < 2; f++) {
        float lt = l[f];
        lt += __shfl_xor(lt, 16);
        lt += __shfl_xor(lt, 32);
        float inv = 1.0f / lt;
        bf16_t* orow = Og + (((size_t)b * NS + q0 + f * 16 + c) * NH + h) * NHD;
#pragma unroll
        for (int nt = 0; nt < 8; nt++) {
            bf16x4 ov;
#pragma unroll
            for (int i = 0; i < 4; i++) ov[i] = (bf16_t)(o[f][nt][i] * inv);
            *(bf16x4*)(orow + nt * 16 + g * 4) = ov;
        }
    }
}

// ---------------------------------------------------------------------------
extern "C" void kernel_launch(void* const* d_in, const int* in_sizes, int n_in,
                              void* d_out, int out_size, void* d_ws, size_t ws_size,
                              hipStream_t stream) {
    const float* hs  = (const float*)d_in[0];
    const float* rot = (const float*)d_in[1];
    const float* Wq  = (const float*)d_in[2];
    const float* bq  = (const float*)d_in[3];
    const float* Wk  = (const float*)d_in[4];
    const float* bk  = (const float*)d_in[5];
    const float* Wv  = (const float*)d_in[6];
    const float* bv  = (const float*)d_in[7];
    const float* gq  = (const float*)d_in[8];
    const float* gk  = (const float*)d_in[9];
    const float* Wo  = (const float*)d_in[10];
    const float* bo  = (const float*)d_in[11];
    float* out = (float*)d_out;

    char* ws = (char*)d_ws;
    bf16_t* Xb  = (bf16_t*)(ws + 0);            // 6144x2048 bf16 = 25165824 B
    bf16_t* Wqb = (bf16_t*)(ws + 25165824);     // 2048x2048 bf16 = 8388608 B
    bf16_t* Wkb = (bf16_t*)(ws + 33554432);
    bf16_t* Wvb = (bf16_t*)(ws + 41943040);
    bf16_t* Wob = (bf16_t*)(ws + 50331648);
    bf16_t* Qb  = (bf16_t*)(ws + 58720256);     // [bh][s][hd] 25165824 B
    bf16_t* Kb  = (bf16_t*)(ws + 83886080);
    bf16_t* VTb = (bf16_t*)(ws + 109051904);    // [bh][hd][s]
    bf16_t* Ob  = (bf16_t*)(ws + 134217728);    // [b][s][h][hd]
    float* Ff = out;  // fp32 proj scratch; final GEMM fully overwrites d_out

    const float QSCALE = 1.4426950408889634f * 0.08838834764831845f; // log2(e)/sqrt(128)

    // 1. casts
    cast_bf16_kernel<<<12288, 256, 0, stream>>>(hs, Xb, NTOK * ND / 4);
    cast_bf16_kernel<<<4096, 256, 0, stream>>>(Wq, Wqb, ND * ND / 4);
    cast_bf16_kernel<<<4096, 256, 0, stream>>>(Wk, Wkb, ND * ND / 4);
    cast_bf16_kernel<<<4096, 256, 0, stream>>>(Wv, Wvb, ND * ND / 4);
    cast_bf16_kernel<<<4096, 256, 0, stream>>>(Wo, Wob, ND * ND / 4);

    dim3 gg(ND / 128, NTOK / 128);   // (16, 48)

    // 2. Q proj -> RMS+RoPE (score scale folded into Q)
    gemm_bt<<<gg, 256, 0, stream>>>(Xb, Wqb, bq, Ff, NTOK, ND, ND);
    rmsrope_kernel<<<NTOK, 256, 0, stream>>>(Ff, gq, rot, Qb, QSCALE);
    // 3. K proj -> RMS+RoPE
    gemm_bt<<<gg, 256, 0, stream>>>(Xb, Wkb, bk, Ff, NTOK, ND, ND);
    rmsrope_kernel<<<NTOK, 256, 0, stream>>>(Ff, gk, rot, Kb, 1.0f);
    // 4. V proj (+bias in GEMM) -> transpose
    gemm_bt<<<gg, 256, 0, stream>>>(Xb, Wvb, bv, Ff, NTOK, ND, ND);
    vtrans_kernel<<<dim3(48, 32), 256, 0, stream>>>(Ff, VTb);
    // 5. attention
    attn_kernel<<<dim3(24, 32), 256, 0, stream>>>(Qb, Kb, VTb, Ob);
    // 6. output projection
    gemm_bt<<<gg, 256, 0, stream>>>(Ob, Wob, bo, out, NTOK, ND, ND);
}

// Round 3
// 753.891 us; speedup vs baseline: 1.2313x; 1.0615x over previous
//
#include <hip/hip_runtime.h>
#include <cstdint>
#include <cstddef>

// ---------------------------------------------------------------------------
// HeliosAttention: hs->QKV proj -> RMSNorm -> RoPE -> 2-segment SDPA -> out proj
// B=2 S=3072 DIM=2048 H=16 HD=128 hist=1024
// ---------------------------------------------------------------------------

typedef __bf16 bf16_t;
typedef __attribute__((ext_vector_type(8))) __bf16 bf16x8;
typedef __attribute__((ext_vector_type(4))) __bf16 bf16x4;
typedef __attribute__((ext_vector_type(4))) float f32x4;
typedef __attribute__((ext_vector_type(4))) unsigned int u32x4;

#define NB   2
#define NS   3072
#define ND   2048
#define NH   16
#define NHD  128
#define NTOK (NB * NS)      // 6144
#define NHIST 1024

__device__ __forceinline__ f32x4 mfma16(bf16x8 a, bf16x8 b, f32x4 c) {
    return __builtin_amdgcn_mfma_f32_16x16x32_bf16(a, b, c, 0, 0, 0);
}

// async global->LDS, 16B per lane. LDS dst MUST be wave-uniform base + lane*16.
__device__ __forceinline__ void async16(const bf16_t* gsrc, bf16_t* ldst) {
    __builtin_amdgcn_global_load_lds(
        (const __attribute__((address_space(1))) void*)gsrc,
        (__attribute__((address_space(3))) void*)ldst,
        16, 0, 0);
}

// ---------------- fp32 -> bf16 elementwise cast ----------------
__global__ __launch_bounds__(256) void cast_bf16_kernel(const float* __restrict__ src,
                                                        bf16_t* __restrict__ dst, int n4) {
    int i = blockIdx.x * 256 + threadIdx.x;
    if (i >= n4) return;
    f32x4 v = ((const f32x4*)src)[i];
    bf16x4 o;
    o[0] = (bf16_t)v[0]; o[1] = (bf16_t)v[1];
    o[2] = (bf16_t)v[2]; o[3] = (bf16_t)v[3];
    ((bf16x4*)dst)[i] = o;
}

// ---------------- C(f32) = A(bf16,MxK) * B(bf16,NxK)^T + bias ----------------
// m97 structure: 128x128 tile, BK=32, global_load_lds width=16 staging into
// UNPADDED stride-32 LDS (lane-contiguous, required by global_load_lds).
__global__ __launch_bounds__(256) void gemm_bt(const bf16_t* __restrict__ A,
                                               const bf16_t* __restrict__ Bm,
                                               const float* __restrict__ bias,
                                               float* __restrict__ C,
                                               int M, int N, int K) {
    __shared__ bf16_t As[128 * 32];
    __shared__ bf16_t Bs[128 * 32];
    const int tid  = threadIdx.x;
    const int wid  = tid >> 6, lane = tid & 63;
    const int g    = lane >> 4, c = lane & 15;
    const int m0   = blockIdx.y * 128, n0 = blockIdx.x * 128;
    const int wm   = (wid & 1) * 64, wn = (wid >> 1) * 64;
    const int srow = tid >> 2, skc = tid & 3;   // thread t: row t>>2, 8-elem chunk t&3

    const bf16_t* Ag0 = A + (size_t)(m0 + srow) * K + skc * 8;
    const bf16_t* Ag1 = A + (size_t)(m0 + srow + 64) * K + skc * 8;
    const bf16_t* Bg0 = Bm + (size_t)(n0 + srow) * K + skc * 8;
    const bf16_t* Bg1 = Bm + (size_t)(n0 + srow + 64) * K + skc * 8;
    bf16_t* Asd0 = As + tid * 8;            // == (srow*32 + skc*8): lane-contiguous
    bf16_t* Asd1 = As + 2048 + tid * 8;
    bf16_t* Bsd0 = Bs + tid * 8;
    bf16_t* Bsd1 = Bs + 2048 + tid * 8;

    f32x4 acc[4][4];
#pragma unroll
    for (int mi = 0; mi < 4; mi++)
#pragma unroll
        for (int ni = 0; ni < 4; ni++)
            acc[mi][ni] = (f32x4){0.f, 0.f, 0.f, 0.f};

    const int nsteps = K / 32;
    for (int ks = 0; ks < nsteps; ks++) {
        __syncthreads();                    // prev tile's readers done
        async16(Ag0 + ks * 32, Asd0);
        async16(Ag1 + ks * 32, Asd1);
        async16(Bg0 + ks * 32, Bsd0);
        async16(Bg1 + ks * 32, Bsd1);
        __syncthreads();                    // implicit vmcnt(0) drain: tile ready

        bf16x8 af[4], bfr[4];
#pragma unroll
        for (int mi = 0; mi < 4; mi++)
            af[mi] = *(const bf16x8*)&As[(wm + mi * 16 + c) * 32 + g * 8];
#pragma unroll
        for (int ni = 0; ni < 4; ni++)
            bfr[ni] = *(const bf16x8*)&Bs[(wn + ni * 16 + c) * 32 + g * 8];
#pragma unroll
        for (int mi = 0; mi < 4; mi++)
#pragma unroll
            for (int ni = 0; ni < 4; ni++)
                acc[mi][ni] = mfma16(af[mi], bfr[ni], acc[mi][ni]);
    }

    float bi[4];
#pragma unroll
    for (int ni = 0; ni < 4; ni++) bi[ni] = bias[n0 + wn + ni * 16 + c];
#pragma unroll
    for (int mi = 0; mi < 4; mi++) {
#pragma unroll
        for (int i = 0; i < 4; i++) {
            int m = m0 + wm + mi * 16 + g * 4 + i;   // C/D: row=(lane>>4)*4+reg, col=lane&15
            float* crow = C + (size_t)m * N + n0 + wn + c;
#pragma unroll
            for (int ni = 0; ni < 4; ni++) crow[ni * 16] = acc[mi][ni][i] + bi[ni];
        }
    }
}

// ---------------- RMSNorm + RoPE + cast, writes [bh][s][hd] bf16 ----------------
// outscale folds (1/sqrt(128))*log2(e) into Q so attention softmax is exp2-domain.
__global__ __launch_bounds__(256) void rmsrope_kernel(const float* __restrict__ X,
                                                      const float* __restrict__ gvec,
                                                      const float* __restrict__ rot,
                                                      bf16_t* __restrict__ dst,
                                                      float outscale) {
    const int t = blockIdx.x;                 // token 0..6143
    const int b = t / NS, s = t % NS;
    const int tid = threadIdx.x;
    const int lane = tid & 63, wid = tid >> 6;
    const float* row = X + (size_t)t * ND;

    f32x4 x0 = *(const f32x4*)(row + tid * 8);
    f32x4 x1 = *(const f32x4*)(row + tid * 8 + 4);
    float ss = 0.f;
#pragma unroll
    for (int u = 0; u < 4; u++) ss += x0[u] * x0[u] + x1[u] * x1[u];
#pragma unroll
    for (int msk = 1; msk < 64; msk <<= 1) ss += __shfl_xor(ss, msk);
    __shared__ float red[4];
    if (lane == 0) red[wid] = ss;
    __syncthreads();
    float tot = red[0] + red[1] + red[2] + red[3];
    float scl = rsqrtf(tot * (1.f / (float)ND) + 1e-6f);

    f32x4 g0 = *(const f32x4*)(gvec + tid * 8);
    f32x4 g1 = *(const f32x4*)(gvec + tid * 8 + 4);
    float y[8];
#pragma unroll
    for (int u = 0; u < 4; u++) { y[u] = x0[u] * scl * g0[u]; y[4 + u] = x1[u] * scl * g1[u]; }

    const int dim = tid * 8, hd = dim & (NHD - 1), h = dim >> 7;
    const float* rr = rot + (size_t)s * (2 * NHD);
    bf16x8 o;
#pragma unroll
    for (int u = 0; u < 4; u++) {
        float cc = rr[hd + 2 * u];               // cos = fc[:128] even idx
        float sn = rr[NHD + hd + 2 * u + 1];     // sin = fc[128:] odd idx
        float e = y[2 * u], od = y[2 * u + 1];
        o[2 * u]     = (bf16_t)((e * cc - od * sn) * outscale);
        o[2 * u + 1] = (bf16_t)((e * sn + od * cc) * outscale);
    }
    *(bf16x8*)(dst + (((size_t)b * NH + h) * NS + s) * NHD + hd) = o;
}

// ---------------- V: +bias done in GEMM; transpose [b][s][h*d] -> [bh][d][s] bf16 ----------
__global__ __launch_bounds__(256) void vtrans_kernel(const float* __restrict__ X,
                                                     bf16_t* __restrict__ VTg) {
    __shared__ bf16_t T[128 * 65];
    const int tid = threadIdx.x;
    const int st = blockIdx.x;                // s-tile of 64
    const int bh = blockIdx.y;
    const int b = bh >> 4, h = bh & 15;
    const int ds = tid >> 4, ssx = tid & 15;
#pragma unroll
    for (int i = 0; i < 4; i++) {
        int sl = ssx + i * 16;
        const float* xr = X + (size_t)(b * NS + st * 64 + sl) * ND + h * NHD;
#pragma unroll
        for (int j = 0; j < 2; j++) {
            int d = ds * 8 + j * 4;
            f32x4 v = *(const f32x4*)(xr + d);
            T[(d + 0) * 65 + sl] = (bf16_t)v[0];
            T[(d + 1) * 65 + sl] = (bf16_t)v[1];
            T[(d + 2) * 65 + sl] = (bf16_t)v[2];
            T[(d + 3) * 65 + sl] = (bf16_t)v[3];
        }
    }
    __syncthreads();
#pragma unroll
    for (int q = 0; q < 4; q++) {
        int chunk = q * 256 + tid;
        int d = chunk >> 3, sc8 = chunk & 7;
        bf16x8 o;
#pragma unroll
        for (int u = 0; u < 8; u++) o[u] = T[d * 65 + sc8 * 8 + u];
        *(bf16x8*)(VTg + ((size_t)bh * NHD + d) * NS + st * 64 + sc8 * 8) = o;
    }
}

// ---------------- flash attention (S^T trick + fixed-max softmax + key chunks) --------
// grid (40, 32 bh): x<8 -> hist q-tile x (keys [0,1024), direct-normalized write);
// x>=8 -> cur q-tile 8+(x-8)/2, key chunk ((x-8)&1)*1536..+1536, writes unnormalized
// f32 partial O-tile + per-q l (fixed-max softmax => partials are exactly additive).
// 1280 blocks = 5*256: exactly fills the 5-blocks/CU LDS-limited residency.
__global__ __launch_bounds__(256) void attn_kernel(const bf16_t* __restrict__ Qg,
                                                   const bf16_t* __restrict__ Kg,
                                                   const bf16_t* __restrict__ Vg,
                                                   bf16_t* __restrict__ Og,
                                                   float* __restrict__ PartA,
                                                   float* __restrict__ PartB,
                                                   float* __restrict__ PartL) {
    __shared__ bf16_t Ks[32 * 136];       // [key][d], stride 136
    __shared__ bf16_t Vs[128 * 40];       // [d][key], stride 40
    __shared__ bf16_t Ps[4][2][16 * 40];  // per-wave per-qfrag, [q][k], kstride 40
    const int tid = threadIdx.x;
    const int wid = tid >> 6, lane = tid & 63;
    const int g = lane >> 4, c = lane & 15;
    const int x = blockIdx.x, bh = blockIdx.y;
    const float FM = 18.0f;

    int qb, k0, niter, tile;
    bool direct;
    if (x < 8) { qb = x; k0 = 0; niter = 32; direct = true; tile = 0; }
    else {
        int t = x - 8;
        qb = 8 + (t >> 1);
        int ch = t & 1;
        k0 = ch * 1536; niter = 48; direct = false;
        tile = (bh * 16 + (qb - 8)) * 2 + ch;      // 0..1023
    }
    const int q0 = qb * 128 + wid * 32;

    // Q B-fragments for 2 q-subtiles, held in registers for the whole kernel
    bf16x8 qf[2][4];
#pragma unroll
    for (int f = 0; f < 2; f++) {
        const bf16_t* qrow = Qg + ((size_t)bh * NS + q0 + f * 16 + c) * NHD;
#pragma unroll
        for (int d = 0; d < 4; d++) qf[f][d] = *(const bf16x8*)(qrow + d * 32 + g * 8);
    }

    f32x4 o[2][8];
#pragma unroll
    for (int f = 0; f < 2; f++)
#pragma unroll
        for (int nt = 0; nt < 8; nt++) o[f][nt] = (f32x4){0.f, 0.f, 0.f, 0.f};
    float l[2] = {0.f, 0.f};

    // staging assignments
    const int skey = tid >> 3, sch = tid & 7;     // K: 32 rows x 8 threads
    const int svd = tid >> 1, svh = tid & 1;      // V: 128 rows x 2 threads

    for (int it = 0; it < niter; it++) {
        const int kb = k0 + it * 32;
        __syncthreads();    // previous iteration's LDS readers done
        {
            const u32x4* ksrc = (const u32x4*)(Kg + ((size_t)bh * NS + kb + skey) * NHD);
            u32x4 k0v = ksrc[sch], k1v = ksrc[sch + 8];
            *(u32x4*)&Ks[skey * 136 + sch * 8]       = k0v;
            *(u32x4*)&Ks[skey * 136 + (sch + 8) * 8] = k1v;
            const u32x4* vsrc = (const u32x4*)(Vg + ((size_t)bh * NHD + svd) * NS + kb);
            u32x4 v0 = vsrc[svh * 2], v1 = vsrc[svh * 2 + 1];
            *(u32x4*)&Vs[svd * 40 + svh * 16]     = v0;
            *(u32x4*)&Vs[svd * 40 + svh * 16 + 8] = v1;
        }
        __syncthreads();

        // S^T = mfma(K-frag, Q-frag): sv[f][kt] C-layout holds
        // S[q = q0+f*16+c][key = kb + kt*16 + g*4 + i]
        f32x4 sv[2][2];
#pragma unroll
        for (int f = 0; f < 2; f++)
#pragma unroll
            for (int kt = 0; kt < 2; kt++) sv[f][kt] = (f32x4){0.f, 0.f, 0.f, 0.f};
#pragma unroll
        for (int kt = 0; kt < 2; kt++)
#pragma unroll
            for (int dd = 0; dd < 4; dd++) {
                bf16x8 kf = *(const bf16x8*)&Ks[(kt * 16 + c) * 136 + dd * 32 + g * 8];
#pragma unroll
                for (int f = 0; f < 2; f++) sv[f][kt] = mfma16(kf, qf[f][dd], sv[f][kt]);
            }

        // fixed-max softmax: p = exp2(s - FM); l accumulates per-lane (deferred
        // reduction); pack k-contiguous bf16x4 -> Ps[q][k]
#pragma unroll
        for (int f = 0; f < 2; f++) {
#pragma unroll
            for (int kt = 0; kt < 2; kt++) {
                bf16x4 pk;
#pragma unroll
                for (int i = 0; i < 4; i++) {
                    float pv = exp2f(sv[f][kt][i] - FM);
                    l[f] += pv;
                    pk[i] = (bf16_t)pv;
                }
                *(bf16x4*)&Ps[wid][f][c * 40 + kt * 16 + g * 4] = pk;
            }
        }
        bf16x8 pf0 = *(const bf16x8*)&Ps[wid][0][c * 40 + g * 8];
        bf16x8 pf1 = *(const bf16x8*)&Ps[wid][1][c * 40 + g * 8];

        // O^T += mfma(V^T-frag, P-frag), contraction over the 32 keys
#pragma unroll
        for (int nt = 0; nt < 8; nt++) {
            bf16x8 vf = *(const bf16x8*)&Vs[(nt * 16 + c) * 40 + g * 8];
            o[0][nt] = mfma16(vf, pf0, o[0][nt]);
            o[1][nt] = mfma16(vf, pf1, o[1][nt]);
        }
    }

    if (direct) {
        // reduce l over g-groups, normalize, store bf16 [b][s][h][d]
        const int b = bh >> 4, h = bh & 15;
#pragma unroll
        for (int f = 0; f < 2; f++) {
            float lt = l[f];
            lt += __shfl_xor(lt, 16);
            lt += __shfl_xor(lt, 32);
            float inv = 1.0f / lt;
            bf16_t* orow = Og + (((size_t)b * NS + q0 + f * 16 + c) * NH + h) * NHD;
#pragma unroll
            for (int nt = 0; nt < 8; nt++) {
                bf16x4 ov;
#pragma unroll
                for (int i = 0; i < 4; i++) ov[i] = (bf16_t)(o[f][nt][i] * inv);
                *(bf16x4*)(orow + nt * 16 + g * 4) = ov;
            }
        }
    } else {
        // write unnormalized f32 partial tile [q 0..127][d 0..127] + l partials
        float* pt = (tile < 768) ? (PartA + (size_t)tile * 16384)
                                 : (PartB + (size_t)(tile - 768) * 16384);
#pragma unroll
        for (int f = 0; f < 2; f++) {
            float lt = l[f];
            lt += __shfl_xor(lt, 16);
            lt += __shfl_xor(lt, 32);
            if (g == 0) PartL[(size_t)tile * 128 + wid * 32 + f * 16 + c] = lt;
            float* prow = pt + (wid * 32 + f * 16 + c) * 128;
#pragma unroll
            for (int nt = 0; nt < 8; nt++)
                *(f32x4*)(prow + nt * 16 + g * 4) = o[f][nt];
        }
    }
}

// ---------------- combine: sum 2 chunk partials, normalize, write bf16 Ob ----------------
// grid (16 cur qtiles, 32 bh), 256 threads.
__global__ __launch_bounds__(256) void combine_kernel(const float* __restrict__ PartA,
                                                      const float* __restrict__ PartB,
                                                      const float* __restrict__ PartL,
                                                      bf16_t* __restrict__ Og) {
    const int qc = blockIdx.x, bh = blockIdx.y;
    const int b = bh >> 4, h = bh & 15;
    const int t0 = (bh * 16 + qc) * 2;            // even; pair never straddles 768
    const float* p0 = (t0 < 768) ? (PartA + (size_t)t0 * 16384)
                                 : (PartB + (size_t)(t0 - 768) * 16384);
    const float* p1 = (t0 + 1 < 768) ? (PartA + (size_t)(t0 + 1) * 16384)
                                     : (PartB + (size_t)(t0 + 1 - 768) * 16384);
    __shared__ float invl[128];
    const int tid = threadIdx.x;
    if (tid < 128)
        invl[tid] = 1.0f / (PartL[(size_t)t0 * 128 + tid] + PartL[(size_t)(t0 + 1) * 128 + tid]);
    __syncthreads();
    const int qb = 8 + qc;
#pragma unroll
    for (int j = 0; j < 16; j++) {
        int idx = j * 1024 + tid * 4;             // flat f32 index in 128x128 tile
        int q = idx >> 7, d = idx & 127;
        f32x4 a = *(const f32x4*)(p0 + idx);
        f32x4 c4 = *(const f32x4*)(p1 + idx);
        float inv = invl[q];
        bf16x4 ov;
#pragma unroll
        for (int i = 0; i < 4; i++) ov[i] = (bf16_t)((a[i] + c4[i]) * inv);
        *(bf16x4*)(Og + (((size_t)b * NS + qb * 128 + q) * NH + h) * NHD + d) = ov;
    }
}

// ---------------------------------------------------------------------------
extern "C" void kernel_launch(void* const* d_in, const int* in_sizes, int n_in,
                              void* d_out, int out_size, void* d_ws, size_t ws_size,
                              hipStream_t stream) {
    const float* hs  = (const float*)d_in[0];
    const float* rot = (const float*)d_in[1];
    const float* Wq  = (const float*)d_in[2];
    const float* bq  = (const float*)d_in[3];
    const float* Wk  = (const float*)d_in[4];
    const float* bk  = (const float*)d_in[5];
    const float* Wv  = (const float*)d_in[6];
    const float* bv  = (const float*)d_in[7];
    const float* gq  = (const float*)d_in[8];
    const float* gk  = (const float*)d_in[9];
    const float* Wo  = (const float*)d_in[10];
    const float* bo  = (const float*)d_in[11];
    float* out = (float*)d_out;

    char* ws = (char*)d_ws;
    bf16_t* Xb  = (bf16_t*)(ws + 0);            // 6144x2048 bf16 = 25165824 B
    bf16_t* Wqb = (bf16_t*)(ws + 25165824);     // 2048x2048 bf16 = 8388608 B
    bf16_t* Wkb = (bf16_t*)(ws + 33554432);
    bf16_t* Wvb = (bf16_t*)(ws + 41943040);
    bf16_t* Wob = (bf16_t*)(ws + 50331648);
    bf16_t* Qb  = (bf16_t*)(ws + 58720256);     // [bh][s][hd] 25165824 B
    bf16_t* Kb  = (bf16_t*)(ws + 83886080);
    bf16_t* VTb = (bf16_t*)(ws + 109051904);    // [bh][hd][s]
    bf16_t* Ob  = (bf16_t*)(ws + 134217728);    // [b][s][h][hd]
    float* Ff = out;  // fp32 proj scratch; final GEMM fully overwrites d_out

    // Partial buffers live in DEAD memory at attention time:
    //  PartA = d_out (V-proj scratch consumed by vtrans; final GEMM runs after combine)
    //  PartB = Xb region (hs bf16, consumed by the 3 QKV GEMMs)
    //  PartL = Wqb region (consumed by Q GEMM)
    float* PartA = out;                     // 768 tiles * 64 KB = 50331648 B exact
    float* PartB = (float*)(ws + 0);        // 256 tiles * 64 KB = 16777216 B <= Xb
    float* PartL = (float*)(ws + 25165824); // 1024*128*4 = 524288 B <= Wqb

    const float QSCALE = 1.4426950408889634f * 0.08838834764831845f; // log2(e)/sqrt(128)

    // 1. casts
    cast_bf16_kernel<<<12288, 256, 0, stream>>>(hs, Xb, NTOK * ND / 4);
    cast_bf16_kernel<<<4096, 256, 0, stream>>>(Wq, Wqb, ND * ND / 4);
    cast_bf16_kernel<<<4096, 256, 0, stream>>>(Wk, Wkb, ND * ND / 4);
    cast_bf16_kernel<<<4096, 256, 0, stream>>>(Wv, Wvb, ND * ND / 4);
    cast_bf16_kernel<<<4096, 256, 0, stream>>>(Wo, Wob, ND * ND / 4);

    dim3 gg(ND / 128, NTOK / 128);   // (16, 48)

    // 2. Q proj -> RMS+RoPE (score scale folded into Q)
    gemm_bt<<<gg, 256, 0, stream>>>(Xb, Wqb, bq, Ff, NTOK, ND, ND);
    rmsrope_kernel<<<NTOK, 256, 0, stream>>>(Ff, gq, rot, Qb, QSCALE);
    // 3. K proj -> RMS+RoPE
    gemm_bt<<<gg, 256, 0, stream>>>(Xb, Wkb, bk, Ff, NTOK, ND, ND);
    rmsrope_kernel<<<NTOK, 256, 0, stream>>>(Ff, gk, rot, Kb, 1.0f);
    // 4. V proj (+bias in GEMM) -> transpose
    gemm_bt<<<gg, 256, 0, stream>>>(Xb, Wvb, bv, Ff, NTOK, ND, ND);
    vtrans_kernel<<<dim3(48, 32), 256, 0, stream>>>(Ff, VTb);
    // 5. attention (balanced chunks) + combine
    attn_kernel<<<dim3(40, 32), 256, 0, stream>>>(Qb, Kb, VTb, Ob, PartA, PartB, PartL);
    combine_kernel<<<dim3(16, 32), 256, 0, stream>>>(PartA, PartB, PartL, Ob);
    // 6. output projection
    gemm_bt<<<gg, 256, 0, stream>>>(Ob, Wob, bo, out, NTOK, ND, ND);
}

// Round 4
// 716.477 us; speedup vs baseline: 1.2956x; 1.0522x over previous
//
#include <hip/hip_runtime.h>
#include <cstdint>
#include <cstddef>

// ---------------------------------------------------------------------------
// HeliosAttention: hs->QKV proj -> RMSNorm -> RoPE -> 2-segment SDPA -> out proj
// B=2 S=3072 DIM=2048 H=16 HD=128 hist=1024
// ---------------------------------------------------------------------------

typedef __bf16 bf16_t;
typedef __attribute__((ext_vector_type(8))) __bf16 bf16x8;
typedef __attribute__((ext_vector_type(4))) __bf16 bf16x4;
typedef __attribute__((ext_vector_type(4))) float f32x4;
typedef __attribute__((ext_vector_type(4))) unsigned int u32x4;

#define NB   2
#define NS   3072
#define ND   2048
#define NH   16
#define NHD  128
#define NTOK (NB * NS)      // 6144
#define NHIST 1024

__device__ __forceinline__ f32x4 mfma16(bf16x8 a, bf16x8 b, f32x4 c) {
    return __builtin_amdgcn_mfma_f32_16x16x32_bf16(a, b, c, 0, 0, 0);
}

// async global->LDS, 16B per lane. LDS dst MUST be wave-uniform base + lane*16.
__device__ __forceinline__ void async16(const bf16_t* gsrc, bf16_t* ldst) {
    __builtin_amdgcn_global_load_lds(
        (const __attribute__((address_space(1))) void*)gsrc,
        (__attribute__((address_space(3))) void*)ldst,
        16, 0, 0);
}

// ---------------- fp32 -> bf16 elementwise cast ----------------
__global__ __launch_bounds__(256) void cast_bf16_kernel(const float* __restrict__ src,
                                                        bf16_t* __restrict__ dst, int n4) {
    int i = blockIdx.x * 256 + threadIdx.x;
    if (i >= n4) return;
    f32x4 v = ((const f32x4*)src)[i];
    bf16x4 o;
    o[0] = (bf16_t)v[0]; o[1] = (bf16_t)v[1];
    o[2] = (bf16_t)v[2]; o[3] = (bf16_t)v[3];
    ((bf16x4*)dst)[i] = o;
}

// ---------------- C(f32) = A(bf16,MxK) * B(bf16,NxK)^T + bias ----------------
// m97 structure: 128x128 tile, BK=32, global_load_lds width=16 staging into
// UNPADDED stride-32 LDS (lane-contiguous, required by global_load_lds).
__global__ __launch_bounds__(256) void gemm_bt(const bf16_t* __restrict__ A,
                                               const bf16_t* __restrict__ Bm,
                                               const float* __restrict__ bias,
                                               float* __restrict__ C,
                                               int M, int N, int K) {
    __shared__ bf16_t As[128 * 32];
    __shared__ bf16_t Bs[128 * 32];
    const int tid  = threadIdx.x;
    const int wid  = tid >> 6, lane = tid & 63;
    const int g    = lane >> 4, c = lane & 15;
    const int m0   = blockIdx.y * 128, n0 = blockIdx.x * 128;
    const int wm   = (wid & 1) * 64, wn = (wid >> 1) * 64;
    const int srow = tid >> 2, skc = tid & 3;   // thread t: row t>>2, 8-elem chunk t&3

    const bf16_t* Ag0 = A + (size_t)(m0 + srow) * K + skc * 8;
    const bf16_t* Ag1 = A + (size_t)(m0 + srow + 64) * K + skc * 8;
    const bf16_t* Bg0 = Bm + (size_t)(n0 + srow) * K + skc * 8;
    const bf16_t* Bg1 = Bm + (size_t)(n0 + srow + 64) * K + skc * 8;
    bf16_t* Asd0 = As + tid * 8;            // == (srow*32 + skc*8): lane-contiguous
    bf16_t* Asd1 = As + 2048 + tid * 8;
    bf16_t* Bsd0 = Bs + tid * 8;
    bf16_t* Bsd1 = Bs + 2048 + tid * 8;

    f32x4 acc[4][4];
#pragma unroll
    for (int mi = 0; mi < 4; mi++)
#pragma unroll
        for (int ni = 0; ni < 4; ni++)
            acc[mi][ni] = (f32x4){0.f, 0.f, 0.f, 0.f};

    const int nsteps = K / 32;
    for (int ks = 0; ks < nsteps; ks++) {
        __syncthreads();                    // prev tile's readers done
        async16(Ag0 + ks * 32, Asd0);
        async16(Ag1 + ks * 32, Asd1);
        async16(Bg0 + ks * 32, Bsd0);
        async16(Bg1 + ks * 32, Bsd1);
        __syncthreads();                    // implicit vmcnt(0) drain: tile ready

        bf16x8 af[4], bfr[4];
#pragma unroll
        for (int mi = 0; mi < 4; mi++)
            af[mi] = *(const bf16x8*)&As[(wm + mi * 16 + c) * 32 + g * 8];
#pragma unroll
        for (int ni = 0; ni < 4; ni++)
            bfr[ni] = *(const bf16x8*)&Bs[(wn + ni * 16 + c) * 32 + g * 8];
#pragma unroll
        for (int mi = 0; mi < 4; mi++)
#pragma unroll
            for (int ni = 0; ni < 4; ni++)
                acc[mi][ni] = mfma16(af[mi], bfr[ni], acc[mi][ni]);
    }

    float bi[4];
#pragma unroll
    for (int ni = 0; ni < 4; ni++) bi[ni] = bias[n0 + wn + ni * 16 + c];
#pragma unroll
    for (int mi = 0; mi < 4; mi++) {
#pragma unroll
        for (int i = 0; i < 4; i++) {
            int m = m0 + wm + mi * 16 + g * 4 + i;   // C/D: row=(lane>>4)*4+reg, col=lane&15
            float* crow = C + (size_t)m * N + n0 + wn + c;
#pragma unroll
            for (int ni = 0; ni < 4; ni++) crow[ni * 16] = acc[mi][ni][i] + bi[ni];
        }
    }
}

// ---------------- RMSNorm + RoPE + cast, writes [bh][s][hd] bf16 ----------------
// outscale folds (1/sqrt(128))*log2(e) into Q so attention softmax is exp2-domain.
__global__ __launch_bounds__(256) void rmsrope_kernel(const float* __restrict__ X,
                                                      const float* __restrict__ gvec,
                                                      const float* __restrict__ rot,
                                                      bf16_t* __restrict__ dst,
                                                      float outscale) {
    const int t = blockIdx.x;                 // token 0..6143
    const int b = t / NS, s = t % NS;
    const int tid = threadIdx.x;
    const int lane = tid & 63, wid = tid >> 6;
    const float* row = X + (size_t)t * ND;

    f32x4 x0 = *(const f32x4*)(row + tid * 8);
    f32x4 x1 = *(const f32x4*)(row + tid * 8 + 4);
    float ss = 0.f;
#pragma unroll
    for (int u = 0; u < 4; u++) ss += x0[u] * x0[u] + x1[u] * x1[u];
#pragma unroll
    for (int msk = 1; msk < 64; msk <<= 1) ss += __shfl_xor(ss, msk);
    __shared__ float red[4];
    if (lane == 0) red[wid] = ss;
    __syncthreads();
    float tot = red[0] + red[1] + red[2] + red[3];
    float scl = rsqrtf(tot * (1.f / (float)ND) + 1e-6f);

    f32x4 g0 = *(const f32x4*)(gvec + tid * 8);
    f32x4 g1 = *(const f32x4*)(gvec + tid * 8 + 4);
    float y[8];
#pragma unroll
    for (int u = 0; u < 4; u++) { y[u] = x0[u] * scl * g0[u]; y[4 + u] = x1[u] * scl * g1[u]; }

    const int dim = tid * 8, hd = dim & (NHD - 1), h = dim >> 7;
    const float* rr = rot + (size_t)s * (2 * NHD);
    bf16x8 o;
#pragma unroll
    for (int u = 0; u < 4; u++) {
        float cc = rr[hd + 2 * u];               // cos = fc[:128] even idx
        float sn = rr[NHD + hd + 2 * u + 1];     // sin = fc[128:] odd idx
        float e = y[2 * u], od = y[2 * u + 1];
        o[2 * u]     = (bf16_t)((e * cc - od * sn) * outscale);
        o[2 * u + 1] = (bf16_t)((e * sn + od * cc) * outscale);
    }
    *(bf16x8*)(dst + (((size_t)b * NH + h) * NS + s) * NHD + hd) = o;
}

// ---------------- V: +bias done in GEMM; transpose [b][s][h*d] -> [bh][d][s] bf16 ----------
__global__ __launch_bounds__(256) void vtrans_kernel(const float* __restrict__ X,
                                                     bf16_t* __restrict__ VTg) {
    __shared__ bf16_t T[128 * 65];
    const int tid = threadIdx.x;
    const int st = blockIdx.x;                // s-tile of 64
    const int bh = blockIdx.y;
    const int b = bh >> 4, h = bh & 15;
    const int ds = tid >> 4, ssx = tid & 15;
#pragma unroll
    for (int i = 0; i < 4; i++) {
        int sl = ssx + i * 16;
        const float* xr = X + (size_t)(b * NS + st * 64 + sl) * ND + h * NHD;
#pragma unroll
        for (int j = 0; j < 2; j++) {
            int d = ds * 8 + j * 4;
            f32x4 v = *(const f32x4*)(xr + d);
            T[(d + 0) * 65 + sl] = (bf16_t)v[0];
            T[(d + 1) * 65 + sl] = (bf16_t)v[1];
            T[(d + 2) * 65 + sl] = (bf16_t)v[2];
            T[(d + 3) * 65 + sl] = (bf16_t)v[3];
        }
    }
    __syncthreads();
#pragma unroll
    for (int q = 0; q < 4; q++) {
        int chunk = q * 256 + tid;
        int d = chunk >> 3, sc8 = chunk & 7;
        bf16x8 o;
#pragma unroll
        for (int u = 0; u < 8; u++) o[u] = T[d * 65 + sc8 * 8 + u];
        *(bf16x8*)(VTg + ((size_t)bh * NHD + d) * NS + st * 64 + sc8 * 8) = o;
    }
}

// ---------------- flash attention ----------------
// S^T trick + fixed-max softmax + balanced key chunks (as R3), plus:
//  * 64 keys per iteration (half the barriers)
//  * register prefetch (depth 1) of next K/V tile: loads fly over compute
//  * single per-wave Ps buffer (no barrier needed; lgkmcnt orders it)
// grid (40, 32 bh): x<8 -> hist q-tile x (keys [0,1024), direct write);
// x>=8 -> cur q-tile 8+(x-8)/2, key chunk ((x-8)&1)*1536, unnormalized f32
// partials + per-q l (fixed-max softmax => partials exactly additive).
// LDS 45056 B -> 3 blocks/CU at the (256,3) VGPR cap of 170.
__global__ __launch_bounds__(256, 3) void attn_kernel(const bf16_t* __restrict__ Qg,
                                                      const bf16_t* __restrict__ Kg,
                                                      const bf16_t* __restrict__ Vg,
                                                      bf16_t* __restrict__ Og,
                                                      float* __restrict__ PartA,
                                                      float* __restrict__ PartB,
                                                      float* __restrict__ PartL) {
    __shared__ bf16_t Ks[64 * 136];       // [key][d], stride 136 (17408 B)
    __shared__ bf16_t Vs[128 * 72];       // [d][key], stride 72  (18432 B)
    __shared__ bf16_t Ps[4][16 * 72];     // per-wave P, [q][key], stride 72 (9216 B)
    const int tid = threadIdx.x;
    const int wid = tid >> 6, lane = tid & 63;
    const int g = lane >> 4, c = lane & 15;
    const int x = blockIdx.x, bh = blockIdx.y;
    const float FM = 18.0f;

    int qb, k0, niter, tile;
    bool direct;
    if (x < 8) { qb = x; k0 = 0; niter = 16; direct = true; tile = 0; }
    else {
        int t = x - 8;
        qb = 8 + (t >> 1);
        int ch = t & 1;
        k0 = ch * 1536; niter = 24; direct = false;
        tile = (bh * 16 + (qb - 8)) * 2 + ch;      // 0..1023
    }
    const int q0 = qb * 128 + wid * 32;

    // Q B-fragments for 2 q-subtiles, held in registers for the whole kernel
    bf16x8 qf[2][4];
#pragma unroll
    for (int f = 0; f < 2; f++) {
        const bf16_t* qrow = Qg + ((size_t)bh * NS + q0 + f * 16 + c) * NHD;
#pragma unroll
        for (int d = 0; d < 4; d++) qf[f][d] = *(const bf16x8*)(qrow + d * 32 + g * 8);
    }

    f32x4 o[2][8];
#pragma unroll
    for (int f = 0; f < 2; f++)
#pragma unroll
        for (int nt = 0; nt < 8; nt++) o[f][nt] = (f32x4){0.f, 0.f, 0.f, 0.f};
    float l[2] = {0.f, 0.f};

    // staging assignments (64-key tiles)
    const int skrow = tid >> 2, skc = tid & 3;    // K: 64 rows x 4 chunks of 8 elem
    const int svd = tid >> 1, svc = tid & 1;      // V: 128 rows x 2 chunks of 8 keys
    const bf16_t* kbase = Kg + ((size_t)bh * NS + skrow) * NHD;
    const bf16_t* vbase = Vg + ((size_t)bh * NHD + svd) * NS;
    bf16_t* pw = &Ps[wid][0];

    u32x4 kreg[4], vreg[4];
    {   // preload iteration 0
        const u32x4* ks = (const u32x4*)(kbase + (size_t)k0 * NHD);
        const u32x4* vs = (const u32x4*)(vbase + k0);
#pragma unroll
        for (int j = 0; j < 4; j++) { kreg[j] = ks[skc + 4 * j]; vreg[j] = vs[svc + 2 * j]; }
    }

    for (int it = 0; it < niter; it++) {
        __syncthreads();    // previous iteration's LDS readers done
#pragma unroll
        for (int j = 0; j < 4; j++) {
            *(u32x4*)&Ks[skrow * 136 + (skc + 4 * j) * 8] = kreg[j];
            *(u32x4*)&Vs[svd * 72 + (svc + 2 * j) * 8]    = vreg[j];
        }
        __syncthreads();
        if (it + 1 < niter) {       // prefetch next tile; latency overlaps compute
            const int kb = k0 + (it + 1) * 64;
            const u32x4* ks = (const u32x4*)(kbase + (size_t)kb * NHD);
            const u32x4* vs = (const u32x4*)(vbase + kb);
#pragma unroll
            for (int j = 0; j < 4; j++) { kreg[j] = ks[skc + 4 * j]; vreg[j] = vs[svc + 2 * j]; }
        }

        // S^T = mfma(K-frag, Q-frag): sv[f][kt] C-layout holds
        // S[q = q0+f*16+c][key = kt*16 + g*4 + i]
        f32x4 sv[2][4];
#pragma unroll
        for (int f = 0; f < 2; f++)
#pragma unroll
            for (int kt = 0; kt < 4; kt++) sv[f][kt] = (f32x4){0.f, 0.f, 0.f, 0.f};
#pragma unroll
        for (int kt = 0; kt < 4; kt++)
#pragma unroll
            for (int dd = 0; dd < 4; dd++) {
                bf16x8 kf = *(const bf16x8*)&Ks[(kt * 16 + c) * 136 + dd * 32 + g * 8];
#pragma unroll
                for (int f = 0; f < 2; f++) sv[f][kt] = mfma16(kf, qf[f][dd], sv[f][kt]);
            }

        // fixed-max softmax p = exp2(s-FM); l per-lane (deferred reduction).
        // Single per-wave Ps buffer reused for f=0,1 (lgkmcnt orders w->r).
        bf16x8 pf[2][2];
#pragma unroll
        for (int f = 0; f < 2; f++) {
#pragma unroll
            for (int kt = 0; kt < 4; kt++) {
                bf16x4 pk;
#pragma unroll
                for (int i = 0; i < 4; i++) {
                    float pv = exp2f(sv[f][kt][i] - FM);
                    l[f] += pv;
                    pk[i] = (bf16_t)pv;
                }
                *(bf16x4*)&pw[c * 72 + kt * 16 + g * 4] = pk;
            }
#pragma unroll
            for (int s = 0; s < 2; s++)
                pf[f][s] = *(const bf16x8*)&pw[c * 72 + s * 32 + g * 8];
        }

        // O^T += mfma(V^T-frag, P-frag), contraction over 64 keys (2 steps)
#pragma unroll
        for (int s = 0; s < 2; s++)
#pragma unroll
            for (int nt = 0; nt < 8; nt++) {
                bf16x8 vf = *(const bf16x8*)&Vs[(nt * 16 + c) * 72 + s * 32 + g * 8];
                o[0][nt] = mfma16(vf, pf[0][s], o[0][nt]);
                o[1][nt] = mfma16(vf, pf[1][s], o[1][nt]);
            }
    }

    if (direct) {
        // reduce l over g-groups, normalize, store bf16 [b][s][h][d]
        const int b = bh >> 4, h = bh & 15;
#pragma unroll
        for (int f = 0; f < 2; f++) {
            float lt = l[f];
            lt += __shfl_xor(lt, 16);
            lt += __shfl_xor(lt, 32);
            float inv = 1.0f / lt;
            bf16_t* orow = Og + (((size_t)b * NS + q0 + f * 16 + c) * NH + h) * NHD;
#pragma unroll
            for (int nt = 0; nt < 8; nt++) {
                bf16x4 ov;
#pragma unroll
                for (int i = 0; i < 4; i++) ov[i] = (bf16_t)(o[f][nt][i] * inv);
                *(bf16x4*)(orow + nt * 16 + g * 4) = ov;
            }
        }
    } else {
        // write unnormalized f32 partial tile [q 0..127][d 0..127] + l partials
        float* pt = (tile < 768) ? (PartA + (size_t)tile * 16384)
                                 : (PartB + (size_t)(tile - 768) * 16384);
#pragma unroll
        for (int f = 0; f < 2; f++) {
            float lt = l[f];
            lt += __shfl_xor(lt, 16);
            lt += __shfl_xor(lt, 32);
            if (g == 0) PartL[(size_t)tile * 128 + wid * 32 + f * 16 + c] = lt;
            float* prow = pt + (wid * 32 + f * 16 + c) * 128;
#pragma unroll
            for (int nt = 0; nt < 8; nt++)
                *(f32x4*)(prow + nt * 16 + g * 4) = o[f][nt];
        }
    }
}

// ---------------- combine: sum 2 chunk partials, normalize, write bf16 Ob ----------------
// grid (16 cur qtiles, 32 bh), 256 threads.
__global__ __launch_bounds__(256) void combine_kernel(const float* __restrict__ PartA,
                                                      const float* __restrict__ PartB,
                                                      const float* __restrict__ PartL,
                                                      bf16_t* __restrict__ Og) {
    const int qc = blockIdx.x, bh = blockIdx.y;
    const int b = bh >> 4, h = bh & 15;
    const int t0 = (bh * 16 + qc) * 2;            // even; pair never straddles 768
    const float* p0 = (t0 < 768) ? (PartA + (size_t)t0 * 16384)
                                 : (PartB + (size_t)(t0 - 768) * 16384);
    const float* p1 = (t0 + 1 < 768) ? (PartA + (size_t)(t0 + 1) * 16384)
                                     : (PartB + (size_t)(t0 + 1 - 768) * 16384);
    __shared__ float invl[128];
    const int tid = threadIdx.x;
    if (tid < 128)
        invl[tid] = 1.0f / (PartL[(size_t)t0 * 128 + tid] + PartL[(size_t)(t0 + 1) * 128 + tid]);
    __syncthreads();
    const int qb = 8 + qc;
#pragma unroll
    for (int j = 0; j < 16; j++) {
        int idx = j * 1024 + tid * 4;             // flat f32 index in 128x128 tile
        int q = idx >> 7, d = idx & 127;
        f32x4 a = *(const f32x4*)(p0 + idx);
        f32x4 c4 = *(const f32x4*)(p1 + idx);
        float inv = invl[q];
        bf16x4 ov;
#pragma unroll
        for (int i = 0; i < 4; i++) ov[i] = (bf16_t)((a[i] + c4[i]) * inv);
        *(bf16x4*)(Og + (((size_t)b * NS + qb * 128 + q) * NH + h) * NHD + d) = ov;
    }
}

// ---------------------------------------------------------------------------
extern "C" void kernel_launch(void* const* d_in, const int* in_sizes, int n_in,
                              void* d_out, int out_size, void* d_ws, size_t ws_size,
                              hipStream_t stream) {
    const float* hs  = (const float*)d_in[0];
    const float* rot = (const float*)d_in[1];
    const float* Wq  = (const float*)d_in[2];
    const float* bq  = (const float*)d_in[3];
    const float* Wk  = (const float*)d_in[4];
    const float* bk  = (const float*)d_in[5];
    const float* Wv  = (const float*)d_in[6];
    const float* bv  = (const float*)d_in[7];
    const float* gq  = (const float*)d_in[8];
    const float* gk  = (const float*)d_in[9];
    const float* Wo  = (const float*)d_in[10];
    const float* bo  = (const float*)d_in[11];
    float* out = (float*)d_out;

    char* ws = (char*)d_ws;
    bf16_t* Xb  = (bf16_t*)(ws + 0);            // 6144x2048 bf16 = 25165824 B
    bf16_t* Wqb = (bf16_t*)(ws + 25165824);     // 2048x2048 bf16 = 8388608 B
    bf16_t* Wkb = (bf16_t*)(ws + 33554432);
    bf16_t* Wvb = (bf16_t*)(ws + 41943040);
    bf16_t* Wob = (bf16_t*)(ws + 50331648);
    bf16_t* Qb  = (bf16_t*)(ws + 58720256);     // [bh][s][hd] 25165824 B
    bf16_t* Kb  = (bf16_t*)(ws + 83886080);
    bf16_t* VTb = (bf16_t*)(ws + 109051904);    // [bh][hd][s]
    bf16_t* Ob  = (bf16_t*)(ws + 134217728);    // [b][s][h][hd]
    float* Ff = out;  // fp32 proj scratch; final GEMM fully overwrites d_out

    // Partial buffers live in DEAD memory at attention time:
    //  PartA = d_out (V-proj scratch consumed by vtrans; final GEMM runs after combine)
    //  PartB = Xb region (hs bf16, consumed by the 3 QKV GEMMs)
    //  PartL = Wqb region (consumed by Q GEMM)
    float* PartA = out;                     // 768 tiles * 64 KB = 50331648 B exact
    float* PartB = (float*)(ws + 0);        // 256 tiles * 64 KB = 16777216 B <= Xb
    float* PartL = (float*)(ws + 25165824); // 1024*128*4 = 524288 B <= Wqb

    const float QSCALE = 1.4426950408889634f * 0.08838834764831845f; // log2(e)/sqrt(128)

    // 1. casts
    cast_bf16_kernel<<<12288, 256, 0, stream>>>(hs, Xb, NTOK * ND / 4);
    cast_bf16_kernel<<<4096, 256, 0, stream>>>(Wq, Wqb, ND * ND / 4);
    cast_bf16_kernel<<<4096, 256, 0, stream>>>(Wk, Wkb, ND * ND / 4);
    cast_bf16_kernel<<<4096, 256, 0, stream>>>(Wv, Wvb, ND * ND / 4);
    cast_bf16_kernel<<<4096, 256, 0, stream>>>(Wo, Wob, ND * ND / 4);

    dim3 gg(ND / 128, NTOK / 128);   // (16, 48)

    // 2. Q proj -> RMS+RoPE (score scale folded into Q)
    gemm_bt<<<gg, 256, 0, stream>>>(Xb, Wqb, bq, Ff, NTOK, ND, ND);
    rmsrope_kernel<<<NTOK, 256, 0, stream>>>(Ff, gq, rot, Qb, QSCALE);
    // 3. K proj -> RMS+RoPE
    gemm_bt<<<gg, 256, 0, stream>>>(Xb, Wkb, bk, Ff, NTOK, ND, ND);
    rmsrope_kernel<<<NTOK, 256, 0, stream>>>(Ff, gk, rot, Kb, 1.0f);
    // 4. V proj (+bias in GEMM) -> transpose
    gemm_bt<<<gg, 256, 0, stream>>>(Xb, Wvb, bv, Ff, NTOK, ND, ND);
    vtrans_kernel<<<dim3(48, 32), 256, 0, stream>>>(Ff, VTb);
    // 5. attention (balanced chunks, 64-key iters, prefetch) + combine
    attn_kernel<<<dim3(40, 32), 256, 0, stream>>>(Qb, Kb, VTb, Ob, PartA, PartB, PartL);
    combine_kernel<<<dim3(16, 32), 256, 0, stream>>>(PartA, PartB, PartL, Ob);
    // 6. output projection
    gemm_bt<<<gg, 256, 0, stream>>>(Ob, Wob, bo, out, NTOK, ND, ND);
}

// Round 5
// 683.776 us; speedup vs baseline: 1.3576x; 1.0478x over previous
//
#include <hip/hip_runtime.h>
#include <cstdint>
#include <cstddef>

// ---------------------------------------------------------------------------
// HeliosAttention: hs->fused QKV proj(bf16 out + sumsq partials) -> in-place
// RMSNorm+RoPE -> 2-segment SDPA (S^T flash, fixed-max softmax, balanced
// chunks) -> out proj.  B=2 S=3072 DIM=2048 H=16 HD=128 hist=1024
// ---------------------------------------------------------------------------

typedef __bf16 bf16_t;
typedef __attribute__((ext_vector_type(8))) __bf16 bf16x8;
typedef __attribute__((ext_vector_type(4))) __bf16 bf16x4;
typedef __attribute__((ext_vector_type(4))) float f32x4;
typedef __attribute__((ext_vector_type(4))) unsigned int u32x4;

#define NB   2
#define NS   3072
#define ND   2048
#define NH   16
#define NHD  128
#define NTOK (NB * NS)      // 6144
#define NHIST 1024
#define N3   (3 * ND)       // 6144 fused QKV row width

__device__ __forceinline__ f32x4 mfma16(bf16x8 a, bf16x8 b, f32x4 c) {
    return __builtin_amdgcn_mfma_f32_16x16x32_bf16(a, b, c, 0, 0, 0);
}

// async global->LDS, 16B per lane. LDS dst MUST be wave-uniform base + lane*16.
__device__ __forceinline__ void async16(const bf16_t* gsrc, bf16_t* ldst) {
    __builtin_amdgcn_global_load_lds(
        (const __attribute__((address_space(1))) void*)gsrc,
        (__attribute__((address_space(3))) void*)ldst,
        16, 0, 0);
}

// ---------------- fp32 -> bf16 elementwise cast ----------------
__global__ __launch_bounds__(256) void cast_bf16_kernel(const float* __restrict__ src,
                                                        bf16_t* __restrict__ dst, int n4) {
    int i = blockIdx.x * 256 + threadIdx.x;
    if (i >= n4) return;
    f32x4 v = ((const f32x4*)src)[i];
    bf16x4 o;
    o[0] = (bf16_t)v[0]; o[1] = (bf16_t)v[1];
    o[2] = (bf16_t)v[2]; o[3] = (bf16_t)v[3];
    ((bf16x4*)dst)[i] = o;
}

// ---------------- concat bq|bk|bv -> 6144 floats ----------------
__global__ __launch_bounds__(256) void bias_concat_kernel(const float* __restrict__ bq,
                                                          const float* __restrict__ bk,
                                                          const float* __restrict__ bv,
                                                          float* __restrict__ dst) {
    int i = blockIdx.x * 256 + threadIdx.x;
    if (i >= N3) return;
    dst[i] = (i < ND) ? bq[i] : (i < 2 * ND ? bk[i - ND] : bv[i - 2 * ND]);
}

// ---------------- fused QKV: C(bf16) = A * B^T + bias, + sumsq partials -------
// m97 staging (global_load_lds w16, unpadded stride-32 LDS), 128x128 tile,
// grid 48x48 = 2304 blocks = 9/CU (the occupancy the 3 split GEMMs lacked).
// Epilogue: bf16 C + per-(row, 64-col-group) sum((acc+bias)^2) partials in
// fp32 (Psum[row*96+grp]) so RMS stats lose no precision to the bf16 store.
__global__ __launch_bounds__(256) void gemm_qkvbf(const bf16_t* __restrict__ A,
                                                  const bf16_t* __restrict__ Bm,
                                                  const float* __restrict__ bias,
                                                  bf16_t* __restrict__ C,
                                                  float* __restrict__ Psum,
                                                  int M, int N, int K) {
    __shared__ bf16_t As[128 * 32];
    __shared__ bf16_t Bs[128 * 32];
    const int tid  = threadIdx.x;
    const int wid  = tid >> 6, lane = tid & 63;
    const int g    = lane >> 4, c = lane & 15;
    const int m0   = blockIdx.y * 128, n0 = blockIdx.x * 128;
    const int wm   = (wid & 1) * 64, wn = (wid >> 1) * 64;
    const int srow = tid >> 2, skc = tid & 3;

    const bf16_t* Ag0 = A + (size_t)(m0 + srow) * K + skc * 8;
    const bf16_t* Ag1 = A + (size_t)(m0 + srow + 64) * K + skc * 8;
    const bf16_t* Bg0 = Bm + (size_t)(n0 + srow) * K + skc * 8;
    const bf16_t* Bg1 = Bm + (size_t)(n0 + srow + 64) * K + skc * 8;
    bf16_t* Asd0 = As + tid * 8;
    bf16_t* Asd1 = As + 2048 + tid * 8;
    bf16_t* Bsd0 = Bs + tid * 8;
    bf16_t* Bsd1 = Bs + 2048 + tid * 8;

    f32x4 acc[4][4];
#pragma unroll
    for (int mi = 0; mi < 4; mi++)
#pragma unroll
        for (int ni = 0; ni < 4; ni++)
            acc[mi][ni] = (f32x4){0.f, 0.f, 0.f, 0.f};

    const int nsteps = K / 32;
    for (int ks = 0; ks < nsteps; ks++) {
        __syncthreads();
        async16(Ag0 + ks * 32, Asd0);
        async16(Ag1 + ks * 32, Asd1);
        async16(Bg0 + ks * 32, Bsd0);
        async16(Bg1 + ks * 32, Bsd1);
        __syncthreads();

        bf16x8 af[4], bfr[4];
#pragma unroll
        for (int mi = 0; mi < 4; mi++)
            af[mi] = *(const bf16x8*)&As[(wm + mi * 16 + c) * 32 + g * 8];
#pragma unroll
        for (int ni = 0; ni < 4; ni++)
            bfr[ni] = *(const bf16x8*)&Bs[(wn + ni * 16 + c) * 32 + g * 8];
#pragma unroll
        for (int mi = 0; mi < 4; mi++)
#pragma unroll
            for (int ni = 0; ni < 4; ni++)
                acc[mi][ni] = mfma16(af[mi], bfr[ni], acc[mi][ni]);
    }

    float bi[4];
#pragma unroll
    for (int ni = 0; ni < 4; ni++) bi[ni] = bias[n0 + wn + ni * 16 + c];
    const int grp = blockIdx.x * 2 + (wid >> 1);   // 64-col group index (0..95)
#pragma unroll
    for (int mi = 0; mi < 4; mi++) {
#pragma unroll
        for (int i = 0; i < 4; i++) {
            int m = m0 + wm + mi * 16 + g * 4 + i;   // C/D: row=(lane>>4)*4+reg
            bf16_t* crow = C + (size_t)m * N + n0 + wn + c;
            float sq = 0.f;
#pragma unroll
            for (int ni = 0; ni < 4; ni++) {
                float v = acc[mi][ni][i] + bi[ni];
                crow[ni * 16] = (bf16_t)v;
                sq += v * v;
            }
#pragma unroll
            for (int msk = 1; msk < 16; msk <<= 1) sq += __shfl_xor(sq, msk);
            if (c == 0) Psum[(size_t)m * 96 + grp] = sq;
        }
    }
}

// ---------------- gemm for O-proj: C(f32) = A * B^T + bias ----------------
__global__ __launch_bounds__(256) void gemm_bt(const bf16_t* __restrict__ A,
                                               const bf16_t* __restrict__ Bm,
                                               const float* __restrict__ bias,
                                               float* __restrict__ C,
                                               int M, int N, int K) {
    __shared__ bf16_t As[128 * 32];
    __shared__ bf16_t Bs[128 * 32];
    const int tid  = threadIdx.x;
    const int wid  = tid >> 6, lane = tid & 63;
    const int g    = lane >> 4, c = lane & 15;
    const int m0   = blockIdx.y * 128, n0 = blockIdx.x * 128;
    const int wm   = (wid & 1) * 64, wn = (wid >> 1) * 64;
    const int srow = tid >> 2, skc = tid & 3;

    const bf16_t* Ag0 = A + (size_t)(m0 + srow) * K + skc * 8;
    const bf16_t* Ag1 = A + (size_t)(m0 + srow + 64) * K + skc * 8;
    const bf16_t* Bg0 = Bm + (size_t)(n0 + srow) * K + skc * 8;
    const bf16_t* Bg1 = Bm + (size_t)(n0 + srow + 64) * K + skc * 8;
    bf16_t* Asd0 = As + tid * 8;
    bf16_t* Asd1 = As + 2048 + tid * 8;
    bf16_t* Bsd0 = Bs + tid * 8;
    bf16_t* Bsd1 = Bs + 2048 + tid * 8;

    f32x4 acc[4][4];
#pragma unroll
    for (int mi = 0; mi < 4; mi++)
#pragma unroll
        for (int ni = 0; ni < 4; ni++)
            acc[mi][ni] = (f32x4){0.f, 0.f, 0.f, 0.f};

    const int nsteps = K / 32;
    for (int ks = 0; ks < nsteps; ks++) {
        __syncthreads();
        async16(Ag0 + ks * 32, Asd0);
        async16(Ag1 + ks * 32, Asd1);
        async16(Bg0 + ks * 32, Bsd0);
        async16(Bg1 + ks * 32, Bsd1);
        __syncthreads();

        bf16x8 af[4], bfr[4];
#pragma unroll
        for (int mi = 0; mi < 4; mi++)
            af[mi] = *(const bf16x8*)&As[(wm + mi * 16 + c) * 32 + g * 8];
#pragma unroll
        for (int ni = 0; ni < 4; ni++)
            bfr[ni] = *(const bf16x8*)&Bs[(wn + ni * 16 + c) * 32 + g * 8];
#pragma unroll
        for (int mi = 0; mi < 4; mi++)
#pragma unroll
            for (int ni = 0; ni < 4; ni++)
                acc[mi][ni] = mfma16(af[mi], bfr[ni], acc[mi][ni]);
    }

    float bi[4];
#pragma unroll
    for (int ni = 0; ni < 4; ni++) bi[ni] = bias[n0 + wn + ni * 16 + c];
#pragma unroll
    for (int mi = 0; mi < 4; mi++) {
#pragma unroll
        for (int i = 0; i < 4; i++) {
            int m = m0 + wm + mi * 16 + g * 4 + i;
            float* crow = C + (size_t)m * N + n0 + wn + c;
#pragma unroll
            for (int ni = 0; ni < 4; ni++) crow[ni * 16] = acc[mi][ni][i] + bi[ni];
        }
    }
}

// ---------------- in-place RMSNorm + RoPE on bf16 QKV rows ----------------
// Block t: reads 32 Q-group + 32 K-group fp32 sumsq partials (exact stats),
// normalizes+ropes the bf16 Q and K segments of row t in place.
// Q gets outscale = log2(e)/sqrt(128) folded in (exp2-domain softmax).
__global__ __launch_bounds__(256) void rmsrope2_kernel(bf16_t* __restrict__ QKV,
                                                       const float* __restrict__ Psum,
                                                       const float* __restrict__ gq,
                                                       const float* __restrict__ gk,
                                                       const float* __restrict__ rot,
                                                       float qscale) {
    const int t = blockIdx.x;
    const int s = t % NS;
    const int tid = threadIdx.x;
    __shared__ float sh[2];
    float p = 0.f;
    if (tid < 64) p = Psum[(size_t)t * 96 + tid];   // 0..31 Q groups, 32..63 K
#pragma unroll
    for (int msk = 1; msk < 32; msk <<= 1) p += __shfl_xor(p, msk);  // halves stay closed
    if (tid == 0) sh[0] = p;
    if (tid == 32) sh[1] = p;
    __syncthreads();
    const float sclQ = rsqrtf(sh[0] * (1.f / (float)ND) + 1e-6f);
    const float sclK = rsqrtf(sh[1] * (1.f / (float)ND) + 1e-6f);

    const int col = tid * 8, hd = col & (NHD - 1);
    const float* rr = rot + (size_t)s * (2 * NHD);
    float cc[4], sn[4];
#pragma unroll
    for (int u = 0; u < 4; u++) {
        cc[u] = rr[hd + 2 * u];
        sn[u] = rr[NHD + hd + 2 * u + 1];
    }
    bf16_t* row = QKV + (size_t)t * N3;

    bf16x8 xq = *(bf16x8*)(row + col);
    bf16x8 xk = *(bf16x8*)(row + ND + col);
    bf16x8 oq, ok;
#pragma unroll
    for (int u = 0; u < 4; u++) {
        float e  = (float)xq[2 * u]     * sclQ * gq[col + 2 * u];
        float od = (float)xq[2 * u + 1] * sclQ * gq[col + 2 * u + 1];
        oq[2 * u]     = (bf16_t)((e * cc[u] - od * sn[u]) * qscale);
        oq[2 * u + 1] = (bf16_t)((e * sn[u] + od * cc[u]) * qscale);
        float ek  = (float)xk[2 * u]     * sclK * gk[col + 2 * u];
        float odk = (float)xk[2 * u + 1] * sclK * gk[col + 2 * u + 1];
        ok[2 * u]     = (bf16_t)(ek * cc[u] - odk * sn[u]);
        ok[2 * u + 1] = (bf16_t)(ek * sn[u] + odk * cc[u]);
    }
    *(bf16x8*)(row + col) = oq;
    *(bf16x8*)(row + ND + col) = ok;
}

// ---------------- V transpose: QKV bf16 V-cols -> [bh][d][s] ----------------
__global__ __launch_bounds__(256) void vtrans_kernel(const bf16_t* __restrict__ QKV,
                                                     bf16_t* __restrict__ VTg) {
    __shared__ bf16_t T[128 * 65];
    const int tid = threadIdx.x;
    const int st = blockIdx.x;                // s-tile of 64
    const int bh = blockIdx.y;
    const int b = bh >> 4, h = bh & 15;
    const int ds = tid >> 4, ssx = tid & 15;
#pragma unroll
    for (int i = 0; i < 4; i++) {
        int sl = ssx + i * 16;
        const bf16_t* xr = QKV + (size_t)(b * NS + st * 64 + sl) * N3 + 2 * ND + h * NHD;
        bf16x8 v = *(const bf16x8*)(xr + ds * 8);
#pragma unroll
        for (int u = 0; u < 8; u++) T[(ds * 8 + u) * 65 + sl] = v[u];
    }
    __syncthreads();
#pragma unroll
    for (int q = 0; q < 4; q++) {
        int chunk = q * 256 + tid;
        int d = chunk >> 3, sc8 = chunk & 7;
        bf16x8 o;
#pragma unroll
        for (int u = 0; u < 8; u++) o[u] = T[d * 65 + sc8 * 8 + u];
        *(bf16x8*)(VTg + ((size_t)bh * NHD + d) * NS + st * 64 + sc8 * 8) = o;
    }
}

// ---------------- flash attention (R4 structure; QKV-strided addressing) -----
// S^T trick, fixed-max softmax, balanced key chunks, 64-key iters, register
// prefetch depth 1, single per-wave Ps.  Q/K read from fused QKV rows
// (stride 6144 elems; per-(token,head) 128-elem chunks are contiguous).
__global__ __launch_bounds__(256, 3) void attn_kernel(const bf16_t* __restrict__ QKV,
                                                      const bf16_t* __restrict__ Vg,
                                                      bf16_t* __restrict__ Og,
                                                      float* __restrict__ PartA,
                                                      float* __restrict__ PartB,
                                                      float* __restrict__ PartL) {
    __shared__ bf16_t Ks[64 * 136];       // [key][d], stride 136 (17408 B)
    __shared__ bf16_t Vs[128 * 72];       // [d][key], stride 72  (18432 B)
    __shared__ bf16_t Ps[4][16 * 72];     // per-wave P, [q][key], stride 72 (9216 B)
    const int tid = threadIdx.x;
    const int wid = tid >> 6, lane = tid & 63;
    const int g = lane >> 4, c = lane & 15;
    const int x = blockIdx.x, bh = blockIdx.y;
    const int b = bh >> 4, h = bh & 15;
    const float FM = 18.0f;

    int qb, k0, niter, tile;
    bool direct;
    if (x < 8) { qb = x; k0 = 0; niter = 16; direct = true; tile = 0; }
    else {
        int t = x - 8;
        qb = 8 + (t >> 1);
        int ch = t & 1;
        k0 = ch * 1536; niter = 24; direct = false;
        tile = (bh * 16 + (qb - 8)) * 2 + ch;      // 0..1023
    }
    const int q0 = qb * 128 + wid * 32;

    // Q B-fragments for 2 q-subtiles, held in registers for the whole kernel
    bf16x8 qf[2][4];
#pragma unroll
    for (int f = 0; f < 2; f++) {
        const bf16_t* qrow = QKV + (size_t)(b * NS + q0 + f * 16 + c) * N3 + h * NHD;
#pragma unroll
        for (int d = 0; d < 4; d++) qf[f][d] = *(const bf16x8*)(qrow + d * 32 + g * 8);
    }

    f32x4 o[2][8];
#pragma unroll
    for (int f = 0; f < 2; f++)
#pragma unroll
        for (int nt = 0; nt < 8; nt++) o[f][nt] = (f32x4){0.f, 0.f, 0.f, 0.f};
    float l[2] = {0.f, 0.f};

    // staging assignments (64-key tiles)
    const int skrow = tid >> 2, skc = tid & 3;    // K: 64 rows x 4 chunks of 8 elem
    const int svd = tid >> 1, svc = tid & 1;      // V: 128 rows x 2 chunks of 8 keys
    const bf16_t* kbase = QKV + (size_t)(b * NS + skrow) * N3 + ND + h * NHD;
    const bf16_t* vbase = Vg + ((size_t)bh * NHD + svd) * NS;
    bf16_t* pw = &Ps[wid][0];

    u32x4 kreg[4], vreg[4];
    {   // preload iteration 0
        const u32x4* ks = (const u32x4*)(kbase + (size_t)k0 * N3);
        const u32x4* vs = (const u32x4*)(vbase + k0);
#pragma unroll
        for (int j = 0; j < 4; j++) { kreg[j] = ks[skc + 4 * j]; vreg[j] = vs[svc + 2 * j]; }
    }

    for (int it = 0; it < niter; it++) {
        __syncthreads();    // previous iteration's LDS readers done
#pragma unroll
        for (int j = 0; j < 4; j++) {
            *(u32x4*)&Ks[skrow * 136 + (skc + 4 * j) * 8] = kreg[j];
            *(u32x4*)&Vs[svd * 72 + (svc + 2 * j) * 8]    = vreg[j];
        }
        __syncthreads();
        if (it + 1 < niter) {       // prefetch next tile; latency overlaps compute
            const int kb = k0 + (it + 1) * 64;
            const u32x4* ks = (const u32x4*)(kbase + (size_t)kb * N3);
            const u32x4* vs = (const u32x4*)(vbase + kb);
#pragma unroll
            for (int j = 0; j < 4; j++) { kreg[j] = ks[skc + 4 * j]; vreg[j] = vs[svc + 2 * j]; }
        }

        // S^T = mfma(K-frag, Q-frag): S[q=q0+f*16+c][key = kt*16 + g*4 + i]
        f32x4 sv[2][4];
#pragma unroll
        for (int f = 0; f < 2; f++)
#pragma unroll
            for (int kt = 0; kt < 4; kt++) sv[f][kt] = (f32x4){0.f, 0.f, 0.f, 0.f};
#pragma unroll
        for (int kt = 0; kt < 4; kt++)
#pragma unroll
            for (int dd = 0; dd < 4; dd++) {
                bf16x8 kf = *(const bf16x8*)&Ks[(kt * 16 + c) * 136 + dd * 32 + g * 8];
#pragma unroll
                for (int f = 0; f < 2; f++) sv[f][kt] = mfma16(kf, qf[f][dd], sv[f][kt]);
            }

        // fixed-max softmax p = exp2(s-FM); l per-lane (deferred reduction).
        bf16x8 pf[2][2];
#pragma unroll
        for (int f = 0; f < 2; f++) {
#pragma unroll
            for (int kt = 0; kt < 4; kt++) {
                bf16x4 pk;
#pragma unroll
                for (int i = 0; i < 4; i++) {
                    float pv = exp2f(sv[f][kt][i] - FM);
                    l[f] += pv;
                    pk[i] = (bf16_t)pv;
                }
                *(bf16x4*)&pw[c * 72 + kt * 16 + g * 4] = pk;
            }
#pragma unroll
            for (int s = 0; s < 2; s++)
                pf[f][s] = *(const bf16x8*)&pw[c * 72 + s * 32 + g * 8];
        }

        // O^T += mfma(V^T-frag, P-frag), contraction over 64 keys
#pragma unroll
        for (int s = 0; s < 2; s++)
#pragma unroll
            for (int nt = 0; nt < 8; nt++) {
                bf16x8 vf = *(const bf16x8*)&Vs[(nt * 16 + c) * 72 + s * 32 + g * 8];
                o[0][nt] = mfma16(vf, pf[0][s], o[0][nt]);
                o[1][nt] = mfma16(vf, pf[1][s], o[1][nt]);
            }
    }

    if (direct) {
        // reduce l over g-groups, normalize, store bf16 [b][s][h][d]
#pragma unroll
        for (int f = 0; f < 2; f++) {
            float lt = l[f];
            lt += __shfl_xor(lt, 16);
            lt += __shfl_xor(lt, 32);
            float inv = 1.0f / lt;
            bf16_t* orow = Og + (((size_t)b * NS + q0 + f * 16 + c) * NH + h) * NHD;
#pragma unroll
            for (int nt = 0; nt < 8; nt++) {
                bf16x4 ov;
#pragma unroll
                for (int i = 0; i < 4; i++) ov[i] = (bf16_t)(o[f][nt][i] * inv);
                *(bf16x4*)(orow + nt * 16 + g * 4) = ov;
            }
        }
    } else {
        // write unnormalized f32 partial tile [q 0..127][d 0..127] + l partials
        float* pt = (tile < 768) ? (PartA + (size_t)tile * 16384)
                                 : (PartB + (size_t)(tile - 768) * 16384);
#pragma unroll
        for (int f = 0; f < 2; f++) {
            float lt = l[f];
            lt += __shfl_xor(lt, 16);
            lt += __shfl_xor(lt, 32);
            if (g == 0) PartL[(size_t)tile * 128 + wid * 32 + f * 16 + c] = lt;
            float* prow = pt + (wid * 32 + f * 16 + c) * 128;
#pragma unroll
            for (int nt = 0; nt < 8; nt++)
                *(f32x4*)(prow + nt * 16 + g * 4) = o[f][nt];
        }
    }
}

// ---------------- combine: sum 2 chunk partials, normalize, write bf16 Ob ----
__global__ __launch_bounds__(256) void combine_kernel(const float* __restrict__ PartA,
                                                      const float* __restrict__ PartB,
                                                      const float* __restrict__ PartL,
                                                      bf16_t* __restrict__ Og) {
    const int qc = blockIdx.x, bh = blockIdx.y;
    const int b = bh >> 4, h = bh & 15;
    const int t0 = (bh * 16 + qc) * 2;            // even; pair never straddles 768
    const float* p0 = (t0 < 768) ? (PartA + (size_t)t0 * 16384)
                                 : (PartB + (size_t)(t0 - 768) * 16384);
    const float* p1 = (t0 + 1 < 768) ? (PartA + (size_t)(t0 + 1) * 16384)
                                     : (PartB + (size_t)(t0 + 1 - 768) * 16384);
    __shared__ float invl[128];
    const int tid = threadIdx.x;
    if (tid < 128)
        invl[tid] = 1.0f / (PartL[(size_t)t0 * 128 + tid] + PartL[(size_t)(t0 + 1) * 128 + tid]);
    __syncthreads();
    const int qb = 8 + qc;
#pragma unroll
    for (int j = 0; j < 16; j++) {
        int idx = j * 1024 + tid * 4;             // flat f32 index in 128x128 tile
        int q = idx >> 7, d = idx & 127;
        f32x4 a = *(const f32x4*)(p0 + idx);
        f32x4 c4 = *(const f32x4*)(p1 + idx);
        float inv = invl[q];
        bf16x4 ov;
#pragma unroll
        for (int i = 0; i < 4; i++) ov[i] = (bf16_t)((a[i] + c4[i]) * inv);
        *(bf16x4*)(Og + (((size_t)b * NS + qb * 128 + q) * NH + h) * NHD + d) = ov;
    }
}

// ---------------------------------------------------------------------------
extern "C" void kernel_launch(void* const* d_in, const int* in_sizes, int n_in,
                              void* d_out, int out_size, void* d_ws, size_t ws_size,
                              hipStream_t stream) {
    const float* hs  = (const float*)d_in[0];
    const float* rot = (const float*)d_in[1];
    const float* Wq  = (const float*)d_in[2];
    const float* bq  = (const float*)d_in[3];
    const float* Wk  = (const float*)d_in[4];
    const float* bk  = (const float*)d_in[5];
    const float* Wv  = (const float*)d_in[6];
    const float* bv  = (const float*)d_in[7];
    const float* gq  = (const float*)d_in[8];
    const float* gk  = (const float*)d_in[9];
    const float* Wo  = (const float*)d_in[10];
    const float* bo  = (const float*)d_in[11];
    float* out = (float*)d_out;

    // ws map (high-water 146800640 B == proven bound from R1-R4):
    //   0        .. 25165824  Xb (hs bf16)            [dead after QKV GEMM]
    //   25165824 .. 50331648  Wqkv bf16 (Wq|Wk|Wv)    [dead after QKV GEMM]
    //   50331648 .. 58720256  Wo bf16
    //   58720256 ..134217728  QKVb bf16 [6144][6144]  (RMS+RoPE applied in place)
    //  134217728 ..146800640  VTb [bh][d][s]
    // Reused dead regions at attention time:
    //   Ob    = ws[0..12.6MB)       (Xb region)
    //   PartB = ws[25165824..42MB)  (Wqkv region, 256 tiles)
    //   PartL = ws[41943040..42.5MB)
    // d_out: Psum (2.36MB) + bqkv (24KB @ +3MB) early; PartA (768 tiles, full
    // 50.3MB) during attention; final GEMM overwrites everything.
    char* ws = (char*)d_ws;
    bf16_t* Xb    = (bf16_t*)(ws + 0);
    bf16_t* Wqkvb = (bf16_t*)(ws + 25165824);
    bf16_t* Wob   = (bf16_t*)(ws + 50331648);
    bf16_t* QKVb  = (bf16_t*)(ws + 58720256);
    bf16_t* VTb   = (bf16_t*)(ws + 134217728);
    bf16_t* Ob    = (bf16_t*)(ws + 0);
    float*  PartB = (float*)(ws + 25165824);
    float*  PartL = (float*)(ws + 41943040);
    float*  Psum  = out;                          // 6144*96*4 = 2359296 B
    float*  bqkv  = (float*)((char*)d_out + 3145728);
    float*  PartA = out;

    const float QSCALE = 1.4426950408889634f * 0.08838834764831845f; // log2(e)/sqrt(128)

    // 1. casts + bias concat
    cast_bf16_kernel<<<12288, 256, 0, stream>>>(hs, Xb, NTOK * ND / 4);
    cast_bf16_kernel<<<4096, 256, 0, stream>>>(Wq, Wqkvb, ND * ND / 4);
    cast_bf16_kernel<<<4096, 256, 0, stream>>>(Wk, Wqkvb + (size_t)ND * ND, ND * ND / 4);
    cast_bf16_kernel<<<4096, 256, 0, stream>>>(Wv, Wqkvb + (size_t)2 * ND * ND, ND * ND / 4);
    cast_bf16_kernel<<<4096, 256, 0, stream>>>(Wo, Wob, ND * ND / 4);
    bias_concat_kernel<<<24, 256, 0, stream>>>(bq, bk, bv, bqkv);

    // 2. fused QKV projection (bf16 out + exact sumsq partials), 2304 blocks
    gemm_qkvbf<<<dim3(N3 / 128, NTOK / 128), 256, 0, stream>>>(Xb, Wqkvb, bqkv,
                                                               QKVb, Psum,
                                                               NTOK, N3, ND);
    // 3. in-place RMSNorm + RoPE on Q,K segments
    rmsrope2_kernel<<<NTOK, 256, 0, stream>>>(QKVb, Psum, gq, gk, rot, QSCALE);
    // 4. V transpose
    vtrans_kernel<<<dim3(48, 32), 256, 0, stream>>>(QKVb, VTb);
    // 5. attention (balanced chunks, 64-key iters, prefetch) + combine
    attn_kernel<<<dim3(40, 32), 256, 0, stream>>>(QKVb, VTb, Ob, PartA, PartB, PartL);
    combine_kernel<<<dim3(16, 32), 256, 0, stream>>>(PartA, PartB, PartL, Ob);
    // 6. output projection
    gemm_bt<<<dim3(ND / 128, NTOK / 128), 256, 0, stream>>>(Ob, Wob, bo, out,
                                                            NTOK, ND, ND);
}